// Round 5
// baseline (12509.315 us; speedup 1.0000x reference)
//
#include <hip/hip_runtime.h>

#define B_ 256
#define T_ 128
#define F_ 784
#define FP_ 800          // F padded to multiple of 32
#define H_ 1024
#define NG_ 4096         // 4*H
#define C_ 10
#define TC_ 16           // time-chunk length
#define MC_ (B_ * TC_)   // rows per chunk = 4096
#define BN_EPS 1e-3f

typedef short s16x8 __attribute__((ext_vector_type(8)));
typedef float f32x4 __attribute__((ext_vector_type(4)));

__device__ __forceinline__ ushort f2bf(float f) {
    union { float f; unsigned u; } v; v.f = f;
    unsigned r = v.u + 0x7FFFu + ((v.u >> 16) & 1u);
    return (ushort)(r >> 16);
}
__device__ __forceinline__ float bf2f(ushort h) {
    union { unsigned u; float f; } v; v.u = ((unsigned)h) << 16;
    return v.f;
}
__device__ __forceinline__ float sigm(float x) {
    return 1.0f / (1.0f + __expf(-x));
}
__device__ __forceinline__ float fast_tanh(float x) {
    x = fminf(15.0f, fmaxf(-15.0f, x));
    float e = __expf(2.0f * x);
    return (e - 1.0f) / (e + 1.0f);
}

// ---------------- prep: BN scale/shift, W_out^T bf16, zero state, zero barrier ----------
__global__ __launch_bounds__(256) void prep_params(
    const float* __restrict__ gamma1, const float* __restrict__ beta1,
    const float* __restrict__ mean1, const float* __restrict__ var1,
    const float* __restrict__ gamma2, const float* __restrict__ beta2,
    const float* __restrict__ mean2, const float* __restrict__ var2,
    const float* __restrict__ W_out,
    float* __restrict__ sc1, float* __restrict__ sh1,
    float* __restrict__ sc2, float* __restrict__ sh2,
    ushort* __restrict__ woutT, float* __restrict__ c_buf, ushort* __restrict__ h_hist,
    unsigned* __restrict__ bar)
{
    int idx = blockIdx.x * 256 + threadIdx.x;
    if (idx == 0) *bar = 0u;
    if (idx < B_ * H_) { c_buf[idx] = 0.0f; h_hist[idx] = 0; }  // h slot 0 = h_{-1} = 0
    if (idx < H_) {
        float s1 = gamma1[idx] * rsqrtf(var1[idx] + BN_EPS);
        sc1[idx] = s1; sh1[idx] = beta1[idx] - mean1[idx] * s1;
        float s2 = gamma2[idx] * rsqrtf(var2[idx] + BN_EPS);
        sc2[idx] = s2; sh2[idx] = beta2[idx] - mean2[idx] * s2;
    }
    if (idx < 16 * H_) {
        int n = idx >> 10, k = idx & (H_ - 1);
        woutT[idx] = (n < C_) ? f2bf(W_out[k * C_ + n]) : (ushort)0;
    }
}

// ---------------- generic f32 (K,N) -> bf16 (N,Kpad) transpose, zero-padded ----------------
__global__ __launch_bounds__(256) void transpose_f32_to_bf16(
    const float* __restrict__ src, ushort* __restrict__ dst, int K, int N, int Kpad)
{
    __shared__ float tile[32][33];
    int tx = threadIdx.x & 31, ty = threadIdx.x >> 5;
    int bx = blockIdx.x, by = blockIdx.y;
    int col = bx * 32 + tx;
    for (int l = 0; l < 4; ++l) {
        int row = by * 32 + ty + l * 8;
        tile[ty + l * 8][tx] = (row < K && col < N) ? src[(long)row * N + col] : 0.0f;
    }
    __syncthreads();
    for (int l = 0; l < 4; ++l) {
        int n = bx * 32 + ty + l * 8;
        int k = by * 32 + tx;
        if (n < N && k < Kpad) dst[(long)n * Kpad + k] = f2bf(tile[tx][ty + l * 8]);
    }
}

// ---- same, but output rows gate-packed: src col n = g*H + u  ->  dst row n2 = u*4 + g ----
__global__ __launch_bounds__(256) void transpose_perm_bf16(
    const float* __restrict__ src, ushort* __restrict__ dst)   // K=H_, N=NG_, Kpad=H_
{
    __shared__ float tile[32][33];
    int tx = threadIdx.x & 31, ty = threadIdx.x >> 5;
    int bx = blockIdx.x, by = blockIdx.y;
    int col = bx * 32 + tx;
    for (int l = 0; l < 4; ++l) {
        int row = by * 32 + ty + l * 8;
        tile[ty + l * 8][tx] = (row < H_) ? src[(long)row * NG_ + col] : 0.0f;
    }
    __syncthreads();
    for (int l = 0; l < 4; ++l) {
        int n = bx * 32 + ty + l * 8;       // original col: g*H + u
        int k = by * 32 + tx;
        int n2 = (n & (H_ - 1)) * 4 + (n >> 10);
        dst[(long)n2 * H_ + k] = f2bf(tile[tx][ty + l * 8]);
    }
}

// ---------------- x chunk -> bf16, chunk-row order (tl*B+b), padded K to 800 ----------------
__global__ __launch_bounds__(256) void convert_x(
    const float* __restrict__ x, ushort* __restrict__ xbf, int t0)
{
    int idx = blockIdx.x * 256 + threadIdx.x;
    int m = idx / 100;
    int kc = idx - m * 100;
    int b = m & (B_ - 1), tl = m >> 8;
    int k = kc * 8;
    ushort o[8];
    if (k < F_) {
        const float* src = x + ((long)b * T_ + t0 + tl) * F_ + k;
        float4 v0 = *(const float4*)src, v1 = *(const float4*)(src + 4);
        o[0]=f2bf(v0.x); o[1]=f2bf(v0.y); o[2]=f2bf(v0.z); o[3]=f2bf(v0.w);
        o[4]=f2bf(v1.x); o[5]=f2bf(v1.y); o[6]=f2bf(v1.z); o[7]=f2bf(v1.w);
    } else {
        for (int i = 0; i < 8; ++i) o[i] = 0;
    }
    *(uint4*)(xbf + (long)m * FP_ + k) = *(uint4*)o;
}

// ---------------- GEMM1 (per chunk, pure bf16): feat = tanh(BN(tanh(xbf @ W_fe + b))) ------
__global__ __launch_bounds__(256) void gemm1_c(
    const ushort* __restrict__ xbf, const ushort* __restrict__ wfeT,
    const float* __restrict__ b_fe, const float* __restrict__ sc1, const float* __restrict__ sh1,
    ushort* __restrict__ feat_c)
{
    __shared__ __align__(16) ushort As[128 * 40];
    __shared__ __align__(16) ushort Bs[128 * 40];
    int tid = threadIdx.x;
    int m0 = blockIdx.y * 128, n0 = blockIdx.x * 128;
    int wave = tid >> 6, lane = tid & 63;
    int wm = wave >> 1, wn = wave & 1;
    int l15 = lane & 15, quad = lane >> 4;

    f32x4 zero = {0.f, 0.f, 0.f, 0.f};
    f32x4 acc[4][4];
    for (int i = 0; i < 4; i++) for (int j = 0; j < 4; j++) acc[i][j] = zero;

    for (int kk = 0; kk < FP_ / 32; ++kk) {
        int kb = kk * 32;
        for (int c = tid; c < 1024; c += 256) {
            if (c < 512) {
                int row = c >> 2, ch = c & 3;
                *(uint4*)&As[row * 40 + ch * 8] =
                    *(const uint4*)(xbf + (long)(m0 + row) * FP_ + kb + ch * 8);
            } else {
                int cb = c - 512;
                int row = cb >> 2, ch = cb & 3;
                *(uint4*)&Bs[row * 40 + ch * 8] =
                    *(const uint4*)(wfeT + (long)(n0 + row) * FP_ + kb + ch * 8);
            }
        }
        __syncthreads();
        s16x8 af[4], bfr[4];
        for (int i = 0; i < 4; i++) af[i]  = *(const s16x8*)&As[(wm * 64 + i * 16 + l15) * 40 + quad * 8];
        for (int j = 0; j < 4; j++) bfr[j] = *(const s16x8*)&Bs[(wn * 64 + j * 16 + l15) * 40 + quad * 8];
        for (int i = 0; i < 4; i++)
            for (int j = 0; j < 4; j++)
                acc[i][j] = __builtin_amdgcn_mfma_f32_16x16x32_bf16(af[i], bfr[j], acc[i][j], 0, 0, 0);
        __syncthreads();
    }
    for (int j = 0; j < 4; j++) {
        int n_g = n0 + wn * 64 + j * 16 + l15;
        float bia = b_fe[n_g], s = sc1[n_g], sh = sh1[n_g];
        for (int i = 0; i < 4; i++) {
            int mb = m0 + wm * 64 + i * 16 + quad * 4;
            for (int r = 0; r < 4; r++) {
                float v = fast_tanh(acc[i][j][r] + bia);
                v = fast_tanh(v * s + sh);
                feat_c[(long)(mb + r) * H_ + n_g] = f2bf(v);
            }
        }
    }
}

// ---------------- GEMM2 (per chunk): zx_c = feat_c @ kernel(packed) -> bf16 (MC_, 4H) ------
__global__ __launch_bounds__(256) void gemm2_c(
    const ushort* __restrict__ feat_c, const ushort* __restrict__ kT2,
    ushort* __restrict__ zx_c)
{
    __shared__ __align__(16) ushort As[128 * 40];
    __shared__ __align__(16) ushort Bs[128 * 40];
    int tid = threadIdx.x;
    int m0 = blockIdx.y * 128, n0 = blockIdx.x * 128;
    int wave = tid >> 6, lane = tid & 63;
    int wm = wave >> 1, wn = wave & 1;
    int l15 = lane & 15, quad = lane >> 4;

    f32x4 zero = {0.f, 0.f, 0.f, 0.f};
    f32x4 acc[4][4];
    for (int i = 0; i < 4; i++) for (int j = 0; j < 4; j++) acc[i][j] = zero;

    for (int kk = 0; kk < H_ / 32; ++kk) {
        int kb = kk * 32;
        for (int c = tid; c < 1024; c += 256) {
            if (c < 512) {
                int row = c >> 2, ch = c & 3;
                *(uint4*)&As[row * 40 + ch * 8] =
                    *(const uint4*)(feat_c + (long)(m0 + row) * H_ + kb + ch * 8);
            } else {
                int cb = c - 512;
                int row = cb >> 2, ch = cb & 3;
                *(uint4*)&Bs[row * 40 + ch * 8] =
                    *(const uint4*)(kT2 + (long)(n0 + row) * H_ + kb + ch * 8);
            }
        }
        __syncthreads();
        s16x8 af[4], bfr[4];
        for (int i = 0; i < 4; i++) af[i]  = *(const s16x8*)&As[(wm * 64 + i * 16 + l15) * 40 + quad * 8];
        for (int j = 0; j < 4; j++) bfr[j] = *(const s16x8*)&Bs[(wn * 64 + j * 16 + l15) * 40 + quad * 8];
        for (int i = 0; i < 4; i++)
            for (int j = 0; j < 4; j++)
                acc[i][j] = __builtin_amdgcn_mfma_f32_16x16x32_bf16(af[i], bfr[j], acc[i][j], 0, 0, 0);
        __syncthreads();
    }
    for (int j = 0; j < 4; j++) {
        int n_g = n0 + wn * 64 + j * 16 + l15;
        for (int i = 0; i < 4; i++) {
            int mb = m0 + wm * 64 + i * 16 + quad * 4;
            for (int r = 0; r < 4; r++)
                zx_c[(long)(mb + r) * NG_ + n_g] = f2bf(acc[i][j][r]);
        }
    }
}

// ---------------- persistent LSTM chunk v2: 128 blocks x 512 thr, 8 units/block -------------
// R-strip (32 packed cols x 1024) in LDS for all 16 steps; z = h @ R via MFMA
// (M=256, N=32, K=1024, gathers h from L2); cell update thread=(batch,half);
// grid barrier = atomicAdd arrival + RELAXED atomic-load poll (no RMW spin).
#define RS2 1032   // LDS row stride (ushorts): 16B-aligned rows
__global__ __launch_bounds__(512, 1) void lstm_chunk(
    ushort* __restrict__ h_hist, float* __restrict__ c_buf,
    const ushort* __restrict__ rT2, const ushort* __restrict__ zx_c,
    const float* __restrict__ bias, const float* __restrict__ pi,
    const float* __restrict__ pf, const float* __restrict__ po,
    unsigned* __restrict__ bar, int ci)
{
    __shared__ ushort Rs[32 * RS2];      // ~66 KB
    __shared__ float zbuf[32][257];      // ~33 KB
    int tid = threadIdx.x;
    int ub = blockIdx.x * 8;             // first hidden unit owned by this block
    int wave = tid >> 6, lane = tid & 63;
    int wm = wave >> 1, wn = wave & 1;   // 4 m-groups x 2 n-groups
    int l15 = lane & 15, quad = lane >> 4;

    // stage R strip: packed rows [ub*4, ub*4+32) x 1024 k
    for (int c = tid; c < 4096; c += 512) {
        int row = c >> 7, kc = c & 127;
        *(uint4*)&Rs[row * RS2 + kc * 8] =
            *(const uint4*)(rT2 + (long)(ub * 4 + row) * H_ + kc * 8);
    }

    int b = tid & 255, half = tid >> 8;  // cell-update identity
    float cst[4];
    *(float4*)cst = *(const float4*)(c_buf + (long)b * H_ + ub + half * 4);
    float bi4[4], bf4[4], bc4[4], bo4[4], pI[4], pF[4], pO[4];
    for (int u = 0; u < 4; ++u) {
        int ug = ub + half * 4 + u;
        bi4[u] = bias[ug];          bf4[u] = bias[H_ + ug];
        bc4[u] = bias[2 * H_ + ug]; bo4[u] = bias[3 * H_ + ug];
        pI[u] = pi[ug]; pF[u] = pf[ug]; pO[u] = po[ug];
    }
    __syncthreads();

    for (int tl = 0; tl < TC_; ++tl) {
        const ushort* hsrc = h_hist +
            (size_t)((tl == 0) ? (ci == 0 ? 0 : TC_) : tl) * (B_ * H_);

        f32x4 acc[4];
        #pragma unroll
        for (int mt = 0; mt < 4; ++mt) acc[mt] = (f32x4){0.f, 0.f, 0.f, 0.f};

        for (int kk = 0; kk < 32; ++kk) {
            s16x8 bfr = *(const s16x8*)&Rs[(wn * 16 + l15) * RS2 + kk * 32 + quad * 8];
            const ushort* hk = hsrc + (size_t)(wm * 64 + l15) * H_ + kk * 32 + quad * 8;
            #pragma unroll
            for (int mt = 0; mt < 4; ++mt) {
                s16x8 af = *(const s16x8*)(hk + (size_t)mt * 16 * H_);
                acc[mt] = __builtin_amdgcn_mfma_f32_16x16x32_bf16(af, bfr, acc[mt], 0, 0, 0);
            }
        }

        // z -> LDS, col-major
        #pragma unroll
        for (int mt = 0; mt < 4; ++mt)
            #pragma unroll
            for (int r = 0; r < 4; ++r)
                zbuf[wn * 16 + l15][wm * 64 + mt * 16 + quad * 4 + r] = acc[mt][r];
        __syncthreads();

        // cell update: zx gate-packed -> one contiguous 32B read per thread
        const ushort* zr = zx_c + ((size_t)tl * B_ + b) * NG_ + ub * 4 + half * 16;
        ushort zv[16];
        *(uint4*)&zv[0] = *(const uint4*)zr;
        *(uint4*)&zv[8] = *(const uint4*)(zr + 8);
        ushort hnew[4];
        #pragma unroll
        for (int u = 0; u < 4; ++u) {
            int cb2 = half * 16 + u * 4;
            float zi = zbuf[cb2 + 0][b] + bi4[u] + bf2f(zv[u * 4 + 0]);
            float zf = zbuf[cb2 + 1][b] + bf4[u] + bf2f(zv[u * 4 + 1]);
            float zc = zbuf[cb2 + 2][b] + bc4[u] + bf2f(zv[u * 4 + 2]);
            float zo = zbuf[cb2 + 3][b] + bo4[u] + bf2f(zv[u * 4 + 3]);
            float co = cst[u];
            float ig = sigm(zi + co * pI[u]);
            float fg = sigm(zf + co * pF[u]);
            float cn = fg * co + ig * fast_tanh(zc);
            float og = sigm(zo + cn * pO[u]);
            cst[u] = cn;
            hnew[u] = f2bf(og * fast_tanh(cn));
        }
        *(ushort4*)(h_hist + (size_t)(tl + 1) * (B_ * H_) + (size_t)b * H_ + ub + half * 4) =
            *(ushort4*)hnew;

        // grid barrier: RMW arrival, read-only poll
        __threadfence();
        __syncthreads();
        if (tid == 0) {
            unsigned target = (unsigned)(ci * TC_ + tl + 1) * 128u;
            atomicAdd(bar, 1u);
            while (__hip_atomic_load(bar, __ATOMIC_RELAXED, __HIP_MEMORY_SCOPE_AGENT) < target)
                __builtin_amdgcn_s_sleep(16);
        }
        __syncthreads();
        __threadfence();
    }
    *(float4*)(c_buf + (long)b * H_ + ub + half * 4) = *(float4*)cst;
}

// ---------------- final (per chunk): out = tanh(BN(h)) @ W_out  (N padded 10->16) ----------
__global__ __launch_bounds__(256) void final_chunk(
    const ushort* __restrict__ h_hist, const ushort* __restrict__ woutT,
    const float* __restrict__ sc2, const float* __restrict__ sh2,
    float* __restrict__ out, int t0)
{
    __shared__ __align__(16) ushort As[128 * 40];
    __shared__ __align__(16) ushort Bs[16 * 40];
    int tid = threadIdx.x;
    long r0 = (long)blockIdx.x * 128;
    const ushort* hbase = h_hist + (long)B_ * H_ + r0 * H_;   // slot 1 onward
    int wave = tid >> 6, lane = tid & 63;
    int l15 = lane & 15, quad = lane >> 4;

    f32x4 zero = {0.f, 0.f, 0.f, 0.f};
    f32x4 acc[2]; acc[0] = zero; acc[1] = zero;

    for (int kk = 0; kk < H_ / 32; ++kk) {
        int kb = kk * 32;
        for (int c = tid; c < 512; c += 256) {
            int row = c >> 2, ch = c & 3;
            int k = kb + ch * 8;
            union { uint4 u4; ushort s[8]; } in, ov;
            in.u4 = *(const uint4*)(hbase + (long)row * H_ + k);
            float4 sa = *(const float4*)(sc2 + k), sb = *(const float4*)(sc2 + k + 4);
            float4 ba = *(const float4*)(sh2 + k), bb = *(const float4*)(sh2 + k + 4);
            ov.s[0] = f2bf(fast_tanh(bf2f(in.s[0]) * sa.x + ba.x));
            ov.s[1] = f2bf(fast_tanh(bf2f(in.s[1]) * sa.y + ba.y));
            ov.s[2] = f2bf(fast_tanh(bf2f(in.s[2]) * sa.z + ba.z));
            ov.s[3] = f2bf(fast_tanh(bf2f(in.s[3]) * sa.w + ba.w));
            ov.s[4] = f2bf(fast_tanh(bf2f(in.s[4]) * sb.x + bb.x));
            ov.s[5] = f2bf(fast_tanh(bf2f(in.s[5]) * sb.y + bb.y));
            ov.s[6] = f2bf(fast_tanh(bf2f(in.s[6]) * sb.z + bb.z));
            ov.s[7] = f2bf(fast_tanh(bf2f(in.s[7]) * sb.w + bb.w));
            *(uint4*)&As[row * 40 + ch * 8] = ov.u4;
        }
        if (tid < 64) {
            int row = tid >> 2, ch = tid & 3;
            *(uint4*)&Bs[row * 40 + ch * 8] = *(const uint4*)(woutT + row * H_ + kb + ch * 8);
        }
        __syncthreads();
        s16x8 bfr = *(const s16x8*)&Bs[l15 * 40 + quad * 8];
        for (int i = 0; i < 2; i++) {
            s16x8 af = *(const s16x8*)&As[(wave * 32 + i * 16 + l15) * 40 + quad * 8];
            acc[i] = __builtin_amdgcn_mfma_f32_16x16x32_bf16(af, bfr, acc[i], 0, 0, 0);
        }
        __syncthreads();
    }
    if (l15 < C_) {
        for (int i = 0; i < 2; i++)
            for (int r = 0; r < 4; r++) {
                long rg = r0 + wave * 32 + i * 16 + quad * 4 + r;  // = tl*B + b
                int tl = (int)(rg >> 8);
                int b  = (int)(rg & (B_ - 1));
                out[((long)b * T_ + t0 + tl) * C_ + l15] = acc[i][r];
            }
    }
}

extern "C" void kernel_launch(void* const* d_in, const int* in_sizes, int n_in,
                              void* d_out, int out_size, void* d_ws, size_t ws_size,
                              hipStream_t stream)
{
    const float* x       = (const float*)d_in[0];
    const float* W_fe    = (const float*)d_in[1];
    const float* b_fe    = (const float*)d_in[2];
    const float* gamma1  = (const float*)d_in[3];
    const float* beta1   = (const float*)d_in[4];
    const float* mean1   = (const float*)d_in[5];
    const float* var1    = (const float*)d_in[6];
    const float* kernelw = (const float*)d_in[7];
    const float* reck    = (const float*)d_in[8];
    const float* bias    = (const float*)d_in[9];
    const float* peep_i  = (const float*)d_in[10];
    const float* peep_f  = (const float*)d_in[11];
    const float* peep_o  = (const float*)d_in[12];
    const float* gamma2  = (const float*)d_in[13];
    const float* beta2   = (const float*)d_in[14];
    const float* mean2   = (const float*)d_in[15];
    const float* var2    = (const float*)d_in[16];
    const float* W_out   = (const float*)d_in[17];
    float* out = (float*)d_out;

    char* ws = (char*)d_ws;
    size_t o = 0;
    ushort* wfeT  = (ushort*)(ws + o); o += (size_t)H_ * FP_ * 2;              // 1.64 MB
    ushort* kT2   = (ushort*)(ws + o); o += (size_t)NG_ * H_ * 2;              // 8.39 MB
    ushort* rT2   = (ushort*)(ws + o); o += (size_t)NG_ * H_ * 2;              // 8.39 MB
    ushort* xbf_c = (ushort*)(ws + o); o += (size_t)MC_ * FP_ * 2;             // 6.55 MB
    ushort* feat_c= (ushort*)(ws + o); o += (size_t)MC_ * H_ * 2;              // 8.39 MB
    ushort* zx_c  = (ushort*)(ws + o); o += (size_t)MC_ * NG_ * 2;             // 33.55 MB
    ushort* h_hist= (ushort*)(ws + o); o += (size_t)(TC_ + 1) * B_ * H_ * 2;   // 8.91 MB
    float*  c_buf = (float*)(ws + o);  o += (size_t)B_ * H_ * 4;               // 1.05 MB
    float*  sc1   = (float*)(ws + o);  o += 4096;
    float*  sh1   = (float*)(ws + o);  o += 4096;
    float*  sc2   = (float*)(ws + o);  o += 4096;
    float*  sh2   = (float*)(ws + o);  o += 4096;
    ushort* woutT = (ushort*)(ws + o); o += 16 * H_ * 2;
    unsigned* bar = (unsigned*)(ws + o); o += 256;
    // total ~77 MB

    prep_params<<<dim3(B_ * H_ / 256), dim3(256), 0, stream>>>(
        gamma1, beta1, mean1, var1, gamma2, beta2, mean2, var2, W_out,
        sc1, sh1, sc2, sh2, woutT, c_buf, h_hist, bar);

    transpose_f32_to_bf16<<<dim3(32, 25), dim3(256), 0, stream>>>(W_fe, wfeT, F_, H_, FP_);
    transpose_perm_bf16<<<dim3(128, 32), dim3(256), 0, stream>>>(kernelw, kT2);
    transpose_perm_bf16<<<dim3(128, 32), dim3(256), 0, stream>>>(reck, rT2);

    for (int ci = 0; ci < T_ / TC_; ++ci) {
        int t0 = ci * TC_;
        convert_x<<<dim3(MC_ * FP_ / 8 / 256), dim3(256), 0, stream>>>(x, xbf_c, t0);
        gemm1_c<<<dim3(H_ / 128, MC_ / 128), dim3(256), 0, stream>>>(
            xbf_c, wfeT, b_fe, sc1, sh1, feat_c);
        gemm2_c<<<dim3(NG_ / 128, MC_ / 128), dim3(256), 0, stream>>>(feat_c, kT2, zx_c);
        lstm_chunk<<<dim3(128), dim3(512), 0, stream>>>(
            h_hist, c_buf, rT2, zx_c, bias, peep_i, peep_f, peep_o, bar, ci);
        final_chunk<<<dim3(MC_ / 128), dim3(256), 0, stream>>>(
            h_hist, woutT, sc2, sh2, out, t0);
    }
}

// Round 6
// 9964.896 us; speedup vs baseline: 1.2553x; 1.2553x over previous
//
#include <hip/hip_runtime.h>

#define B_ 256
#define T_ 128
#define F_ 784
#define FP_ 800          // F padded to multiple of 32
#define H_ 1024
#define NG_ 4096         // 4*H
#define C_ 10
#define TC_ 16           // time-chunk length
#define MC_ (B_ * TC_)   // rows per chunk = 4096
#define BN_EPS 1e-3f

typedef short s16x8 __attribute__((ext_vector_type(8)));
typedef float f32x4 __attribute__((ext_vector_type(4)));
typedef unsigned long long u64;

__device__ __forceinline__ ushort f2bf(float f) {
    union { float f; unsigned u; } v; v.f = f;
    unsigned r = v.u + 0x7FFFu + ((v.u >> 16) & 1u);
    return (ushort)(r >> 16);
}
__device__ __forceinline__ float bf2f(ushort h) {
    union { unsigned u; float f; } v; v.u = ((unsigned)h) << 16;
    return v.f;
}
__device__ __forceinline__ float sigm(float x) {
    return 1.0f / (1.0f + __expf(-x));
}
__device__ __forceinline__ float fast_tanh(float x) {
    x = fminf(15.0f, fmaxf(-15.0f, x));
    float e = __expf(2.0f * x);
    return (e - 1.0f) / (e + 1.0f);
}

// ---------------- prep: BN scale/shift, W_out^T bf16, zero state, zero barrier ----------
__global__ __launch_bounds__(256) void prep_params(
    const float* __restrict__ gamma1, const float* __restrict__ beta1,
    const float* __restrict__ mean1, const float* __restrict__ var1,
    const float* __restrict__ gamma2, const float* __restrict__ beta2,
    const float* __restrict__ mean2, const float* __restrict__ var2,
    const float* __restrict__ W_out,
    float* __restrict__ sc1, float* __restrict__ sh1,
    float* __restrict__ sc2, float* __restrict__ sh2,
    ushort* __restrict__ woutT, float* __restrict__ c_buf, ushort* __restrict__ h_hist,
    unsigned* __restrict__ bar)
{
    int idx = blockIdx.x * 256 + threadIdx.x;
    if (idx == 0) *bar = 0u;
    if (idx < B_ * H_) { c_buf[idx] = 0.0f; h_hist[idx] = 0; }  // h slot 0 = h_{-1} = 0
    if (idx < H_) {
        float s1 = gamma1[idx] * rsqrtf(var1[idx] + BN_EPS);
        sc1[idx] = s1; sh1[idx] = beta1[idx] - mean1[idx] * s1;
        float s2 = gamma2[idx] * rsqrtf(var2[idx] + BN_EPS);
        sc2[idx] = s2; sh2[idx] = beta2[idx] - mean2[idx] * s2;
    }
    if (idx < 16 * H_) {
        int n = idx >> 10, k = idx & (H_ - 1);
        woutT[idx] = (n < C_) ? f2bf(W_out[k * C_ + n]) : (ushort)0;
    }
}

// ---------------- generic f32 (K,N) -> bf16 (N,Kpad) transpose, zero-padded ----------------
__global__ __launch_bounds__(256) void transpose_f32_to_bf16(
    const float* __restrict__ src, ushort* __restrict__ dst, int K, int N, int Kpad)
{
    __shared__ float tile[32][33];
    int tx = threadIdx.x & 31, ty = threadIdx.x >> 5;
    int bx = blockIdx.x, by = blockIdx.y;
    int col = bx * 32 + tx;
    for (int l = 0; l < 4; ++l) {
        int row = by * 32 + ty + l * 8;
        tile[ty + l * 8][tx] = (row < K && col < N) ? src[(long)row * N + col] : 0.0f;
    }
    __syncthreads();
    for (int l = 0; l < 4; ++l) {
        int n = bx * 32 + ty + l * 8;
        int k = by * 32 + tx;
        if (n < N && k < Kpad) dst[(long)n * Kpad + k] = f2bf(tile[tx][ty + l * 8]);
    }
}

// ---- same, but output rows gate-packed: src col n = g*H + u  ->  dst row n2 = u*4 + g ----
__global__ __launch_bounds__(256) void transpose_perm_bf16(
    const float* __restrict__ src, ushort* __restrict__ dst)   // K=H_, N=NG_, Kpad=H_
{
    __shared__ float tile[32][33];
    int tx = threadIdx.x & 31, ty = threadIdx.x >> 5;
    int bx = blockIdx.x, by = blockIdx.y;
    int col = bx * 32 + tx;
    for (int l = 0; l < 4; ++l) {
        int row = by * 32 + ty + l * 8;
        tile[ty + l * 8][tx] = (row < H_) ? src[(long)row * NG_ + col] : 0.0f;
    }
    __syncthreads();
    for (int l = 0; l < 4; ++l) {
        int n = bx * 32 + ty + l * 8;       // original col: g*H + u
        int k = by * 32 + tx;
        int n2 = (n & (H_ - 1)) * 4 + (n >> 10);
        dst[(long)n2 * H_ + k] = f2bf(tile[tx][ty + l * 8]);
    }
}

// ---------------- x chunk -> bf16, chunk-row order (tl*B+b), padded K to 800 ----------------
__global__ __launch_bounds__(256) void convert_x(
    const float* __restrict__ x, ushort* __restrict__ xbf, int t0)
{
    int idx = blockIdx.x * 256 + threadIdx.x;
    int m = idx / 100;
    int kc = idx - m * 100;
    int b = m & (B_ - 1), tl = m >> 8;
    int k = kc * 8;
    ushort o[8];
    if (k < F_) {
        const float* src = x + ((long)b * T_ + t0 + tl) * F_ + k;
        float4 v0 = *(const float4*)src, v1 = *(const float4*)(src + 4);
        o[0]=f2bf(v0.x); o[1]=f2bf(v0.y); o[2]=f2bf(v0.z); o[3]=f2bf(v0.w);
        o[4]=f2bf(v1.x); o[5]=f2bf(v1.y); o[6]=f2bf(v1.z); o[7]=f2bf(v1.w);
    } else {
        for (int i = 0; i < 8; ++i) o[i] = 0;
    }
    *(uint4*)(xbf + (long)m * FP_ + k) = *(uint4*)o;
}

// ---------------- GEMM1 (per chunk, pure bf16): feat = tanh(BN(tanh(xbf @ W_fe + b))) ------
__global__ __launch_bounds__(256) void gemm1_c(
    const ushort* __restrict__ xbf, const ushort* __restrict__ wfeT,
    const float* __restrict__ b_fe, const float* __restrict__ sc1, const float* __restrict__ sh1,
    ushort* __restrict__ feat_c)
{
    __shared__ __align__(16) ushort As[128 * 40];
    __shared__ __align__(16) ushort Bs[128 * 40];
    int tid = threadIdx.x;
    int m0 = blockIdx.y * 128, n0 = blockIdx.x * 128;
    int wave = tid >> 6, lane = tid & 63;
    int wm = wave >> 1, wn = wave & 1;
    int l15 = lane & 15, quad = lane >> 4;

    f32x4 zero = {0.f, 0.f, 0.f, 0.f};
    f32x4 acc[4][4];
    for (int i = 0; i < 4; i++) for (int j = 0; j < 4; j++) acc[i][j] = zero;

    for (int kk = 0; kk < FP_ / 32; ++kk) {
        int kb = kk * 32;
        for (int c = tid; c < 1024; c += 256) {
            if (c < 512) {
                int row = c >> 2, ch = c & 3;
                *(uint4*)&As[row * 40 + ch * 8] =
                    *(const uint4*)(xbf + (long)(m0 + row) * FP_ + kb + ch * 8);
            } else {
                int cb = c - 512;
                int row = cb >> 2, ch = cb & 3;
                *(uint4*)&Bs[row * 40 + ch * 8] =
                    *(const uint4*)(wfeT + (long)(n0 + row) * FP_ + kb + ch * 8);
            }
        }
        __syncthreads();
        s16x8 af[4], bfr[4];
        for (int i = 0; i < 4; i++) af[i]  = *(const s16x8*)&As[(wm * 64 + i * 16 + l15) * 40 + quad * 8];
        for (int j = 0; j < 4; j++) bfr[j] = *(const s16x8*)&Bs[(wn * 64 + j * 16 + l15) * 40 + quad * 8];
        for (int i = 0; i < 4; i++)
            for (int j = 0; j < 4; j++)
                acc[i][j] = __builtin_amdgcn_mfma_f32_16x16x32_bf16(af[i], bfr[j], acc[i][j], 0, 0, 0);
        __syncthreads();
    }
    for (int j = 0; j < 4; j++) {
        int n_g = n0 + wn * 64 + j * 16 + l15;
        float bia = b_fe[n_g], s = sc1[n_g], sh = sh1[n_g];
        for (int i = 0; i < 4; i++) {
            int mb = m0 + wm * 64 + i * 16 + quad * 4;
            for (int r = 0; r < 4; r++) {
                float v = fast_tanh(acc[i][j][r] + bia);
                v = fast_tanh(v * s + sh);
                feat_c[(long)(mb + r) * H_ + n_g] = f2bf(v);
            }
        }
    }
}

// ---------------- GEMM2 (per chunk): zx_c = feat_c @ kernel(packed) -> bf16 (MC_, 4H) ------
__global__ __launch_bounds__(256) void gemm2_c(
    const ushort* __restrict__ feat_c, const ushort* __restrict__ kT2,
    ushort* __restrict__ zx_c)
{
    __shared__ __align__(16) ushort As[128 * 40];
    __shared__ __align__(16) ushort Bs[128 * 40];
    int tid = threadIdx.x;
    int m0 = blockIdx.y * 128, n0 = blockIdx.x * 128;
    int wave = tid >> 6, lane = tid & 63;
    int wm = wave >> 1, wn = wave & 1;
    int l15 = lane & 15, quad = lane >> 4;

    f32x4 zero = {0.f, 0.f, 0.f, 0.f};
    f32x4 acc[4][4];
    for (int i = 0; i < 4; i++) for (int j = 0; j < 4; j++) acc[i][j] = zero;

    for (int kk = 0; kk < H_ / 32; ++kk) {
        int kb = kk * 32;
        for (int c = tid; c < 1024; c += 256) {
            if (c < 512) {
                int row = c >> 2, ch = c & 3;
                *(uint4*)&As[row * 40 + ch * 8] =
                    *(const uint4*)(feat_c + (long)(m0 + row) * H_ + kb + ch * 8);
            } else {
                int cb = c - 512;
                int row = cb >> 2, ch = cb & 3;
                *(uint4*)&Bs[row * 40 + ch * 8] =
                    *(const uint4*)(kT2 + (long)(n0 + row) * H_ + kb + ch * 8);
            }
        }
        __syncthreads();
        s16x8 af[4], bfr[4];
        for (int i = 0; i < 4; i++) af[i]  = *(const s16x8*)&As[(wm * 64 + i * 16 + l15) * 40 + quad * 8];
        for (int j = 0; j < 4; j++) bfr[j] = *(const s16x8*)&Bs[(wn * 64 + j * 16 + l15) * 40 + quad * 8];
        for (int i = 0; i < 4; i++)
            for (int j = 0; j < 4; j++)
                acc[i][j] = __builtin_amdgcn_mfma_f32_16x16x32_bf16(af[i], bfr[j], acc[i][j], 0, 0, 0);
        __syncthreads();
    }
    for (int j = 0; j < 4; j++) {
        int n_g = n0 + wn * 64 + j * 16 + l15;
        for (int i = 0; i < 4; i++) {
            int mb = m0 + wm * 64 + i * 16 + quad * 4;
            for (int r = 0; r < 4; r++)
                zx_c[(long)(mb + r) * NG_ + n_g] = f2bf(acc[i][j][r]);
        }
    }
}

// ---------------- persistent LSTM chunk v3: fence-free, agent-coherent h traffic ------------
// 128 blocks x 512 thr, 8 units/block; R strip in LDS for all 16 steps.
// h is read/written ONLY via agent-scope relaxed atomics (served at the device coherence
// point, cross-XCD coherent) -> no __threadfence, no per-step L2 writeback/invalidate.
// Store->arrival ordering: __syncthreads() drains vmcnt before s_barrier (compiler-emitted).
#define RS2 1032   // LDS row stride (ushorts): 16B-aligned rows
__global__ __launch_bounds__(512, 1) void lstm_chunk(
    ushort* __restrict__ h_hist, float* __restrict__ c_buf,
    const ushort* __restrict__ rT2, const ushort* __restrict__ zx_c,
    const float* __restrict__ bias, const float* __restrict__ pi,
    const float* __restrict__ pf, const float* __restrict__ po,
    unsigned* __restrict__ bar, int ci)
{
    __shared__ ushort Rs[32 * RS2];      // ~66 KB
    __shared__ float zbuf[32][257];      // ~33 KB
    int tid = threadIdx.x;
    int ub = blockIdx.x * 8;             // first hidden unit owned by this block
    int wave = tid >> 6, lane = tid & 63;
    int wm = wave >> 1, wn = wave & 1;   // 4 m-groups x 2 n-groups
    int l15 = lane & 15, quad = lane >> 4;

    // stage R strip: packed rows [ub*4, ub*4+32) x 1024 k
    for (int c = tid; c < 4096; c += 512) {
        int row = c >> 7, kc = c & 127;
        *(uint4*)&Rs[row * RS2 + kc * 8] =
            *(const uint4*)(rT2 + (long)(ub * 4 + row) * H_ + kc * 8);
    }

    int b = tid & 255, half = tid >> 8;  // cell-update identity
    float cst[4];
    *(float4*)cst = *(const float4*)(c_buf + (long)b * H_ + ub + half * 4);
    float bi4[4], bf4[4], bc4[4], bo4[4], pI[4], pF[4], pO[4];
    for (int u = 0; u < 4; ++u) {
        int ug = ub + half * 4 + u;
        bi4[u] = bias[ug];          bf4[u] = bias[H_ + ug];
        bc4[u] = bias[2 * H_ + ug]; bo4[u] = bias[3 * H_ + ug];
        pI[u] = pi[ug]; pF[u] = pf[ug]; pO[u] = po[ug];
    }
    __syncthreads();

    for (int tl = 0; tl < TC_; ++tl) {
        const ushort* hsrc = h_hist +
            (size_t)((tl == 0) ? (ci == 0 ? 0 : TC_) : tl) * (B_ * H_);

        f32x4 acc[4];
        #pragma unroll
        for (int mt = 0; mt < 4; ++mt) acc[mt] = (f32x4){0.f, 0.f, 0.f, 0.f};

        for (int kk = 0; kk < 32; ++kk) {
            s16x8 bfr = *(const s16x8*)&Rs[(wn * 16 + l15) * RS2 + kk * 32 + quad * 8];
            const ushort* hk = hsrc + (size_t)(wm * 64 + l15) * H_ + kk * 32 + quad * 8;
            #pragma unroll
            for (int mt = 0; mt < 4; ++mt) {
                const u64* hp = (const u64*)(hk + (size_t)mt * 16 * H_);
                union { s16x8 v; u64 q[2]; } af;
                af.q[0] = __hip_atomic_load(hp,     __ATOMIC_RELAXED, __HIP_MEMORY_SCOPE_AGENT);
                af.q[1] = __hip_atomic_load(hp + 1, __ATOMIC_RELAXED, __HIP_MEMORY_SCOPE_AGENT);
                acc[mt] = __builtin_amdgcn_mfma_f32_16x16x32_bf16(af.v, bfr, acc[mt], 0, 0, 0);
            }
        }

        // z -> LDS, col-major
        #pragma unroll
        for (int mt = 0; mt < 4; ++mt)
            #pragma unroll
            for (int r = 0; r < 4; ++r)
                zbuf[wn * 16 + l15][wm * 64 + mt * 16 + quad * 4 + r] = acc[mt][r];
        __syncthreads();

        // cell update: zx gate-packed -> one contiguous 32B read per thread
        const ushort* zr = zx_c + ((size_t)tl * B_ + b) * NG_ + ub * 4 + half * 16;
        ushort zv[16];
        *(uint4*)&zv[0] = *(const uint4*)zr;
        *(uint4*)&zv[8] = *(const uint4*)(zr + 8);
        ushort hnew[4];
        #pragma unroll
        for (int u = 0; u < 4; ++u) {
            int cb2 = half * 16 + u * 4;
            float zi = zbuf[cb2 + 0][b] + bi4[u] + bf2f(zv[u * 4 + 0]);
            float zf = zbuf[cb2 + 1][b] + bf4[u] + bf2f(zv[u * 4 + 1]);
            float zc = zbuf[cb2 + 2][b] + bc4[u] + bf2f(zv[u * 4 + 2]);
            float zo = zbuf[cb2 + 3][b] + bo4[u] + bf2f(zv[u * 4 + 3]);
            float co = cst[u];
            float ig = sigm(zi + co * pI[u]);
            float fg = sigm(zf + co * pF[u]);
            float cn = fg * co + ig * fast_tanh(zc);
            float og = sigm(zo + cn * pO[u]);
            cst[u] = cn;
            hnew[u] = f2bf(og * fast_tanh(cn));
        }
        union { ushort s[4]; u64 q; } hv;
        hv.s[0] = hnew[0]; hv.s[1] = hnew[1]; hv.s[2] = hnew[2]; hv.s[3] = hnew[3];
        __hip_atomic_store(
            (u64*)(h_hist + (size_t)(tl + 1) * (B_ * H_) + (size_t)b * H_ + ub + half * 4),
            hv.q, __ATOMIC_RELAXED, __HIP_MEMORY_SCOPE_AGENT);

        // grid barrier: syncthreads drains vmcnt (h stores complete at coherence point),
        // then RMW arrival + read-only poll. No fences.
        __syncthreads();
        if (tid == 0) {
            unsigned target = (unsigned)(ci * TC_ + tl + 1) * 128u;
            __hip_atomic_fetch_add(bar, 1u, __ATOMIC_RELAXED, __HIP_MEMORY_SCOPE_AGENT);
            while (__hip_atomic_load(bar, __ATOMIC_RELAXED, __HIP_MEMORY_SCOPE_AGENT) < target)
                __builtin_amdgcn_s_sleep(2);
        }
        __syncthreads();
    }
    *(float4*)(c_buf + (long)b * H_ + ub + half * 4) = *(float4*)cst;
}

// ---------------- final (per chunk): out = tanh(BN(h)) @ W_out  (N padded 10->16) ----------
__global__ __launch_bounds__(256) void final_chunk(
    const ushort* __restrict__ h_hist, const ushort* __restrict__ woutT,
    const float* __restrict__ sc2, const float* __restrict__ sh2,
    float* __restrict__ out, int t0)
{
    __shared__ __align__(16) ushort As[128 * 40];
    __shared__ __align__(16) ushort Bs[16 * 40];
    int tid = threadIdx.x;
    long r0 = (long)blockIdx.x * 128;
    const ushort* hbase = h_hist + (long)B_ * H_ + r0 * H_;   // slot 1 onward
    int wave = tid >> 6, lane = tid & 63;
    int l15 = lane & 15, quad = lane >> 4;

    f32x4 zero = {0.f, 0.f, 0.f, 0.f};
    f32x4 acc[2]; acc[0] = zero; acc[1] = zero;

    for (int kk = 0; kk < H_ / 32; ++kk) {
        int kb = kk * 32;
        for (int c = tid; c < 512; c += 256) {
            int row = c >> 2, ch = c & 3;
            int k = kb + ch * 8;
            union { uint4 u4; ushort s[8]; } in, ov;
            in.u4 = *(const uint4*)(hbase + (long)row * H_ + k);
            float4 sa = *(const float4*)(sc2 + k), sb = *(const float4*)(sc2 + k + 4);
            float4 ba = *(const float4*)(sh2 + k), bb = *(const float4*)(sh2 + k + 4);
            ov.s[0] = f2bf(fast_tanh(bf2f(in.s[0]) * sa.x + ba.x));
            ov.s[1] = f2bf(fast_tanh(bf2f(in.s[1]) * sa.y + ba.y));
            ov.s[2] = f2bf(fast_tanh(bf2f(in.s[2]) * sa.z + ba.z));
            ov.s[3] = f2bf(fast_tanh(bf2f(in.s[3]) * sa.w + ba.w));
            ov.s[4] = f2bf(fast_tanh(bf2f(in.s[4]) * sb.x + bb.x));
            ov.s[5] = f2bf(fast_tanh(bf2f(in.s[5]) * sb.y + bb.y));
            ov.s[6] = f2bf(fast_tanh(bf2f(in.s[6]) * sb.z + bb.z));
            ov.s[7] = f2bf(fast_tanh(bf2f(in.s[7]) * sb.w + bb.w));
            *(uint4*)&As[row * 40 + ch * 8] = ov.u4;
        }
        if (tid < 64) {
            int row = tid >> 2, ch = tid & 3;
            *(uint4*)&Bs[row * 40 + ch * 8] = *(const uint4*)(woutT + row * H_ + kb + ch * 8);
        }
        __syncthreads();
        s16x8 bfr = *(const s16x8*)&Bs[l15 * 40 + quad * 8];
        for (int i = 0; i < 2; i++) {
            s16x8 af = *(const s16x8*)&As[(wave * 32 + i * 16 + l15) * 40 + quad * 8];
            acc[i] = __builtin_amdgcn_mfma_f32_16x16x32_bf16(af, bfr, acc[i], 0, 0, 0);
        }
        __syncthreads();
    }
    if (l15 < C_) {
        for (int i = 0; i < 2; i++)
            for (int r = 0; r < 4; r++) {
                long rg = r0 + wave * 32 + i * 16 + quad * 4 + r;  // = tl*B + b
                int tl = (int)(rg >> 8);
                int b  = (int)(rg & (B_ - 1));
                out[((long)b * T_ + t0 + tl) * C_ + l15] = acc[i][r];
            }
    }
}

extern "C" void kernel_launch(void* const* d_in, const int* in_sizes, int n_in,
                              void* d_out, int out_size, void* d_ws, size_t ws_size,
                              hipStream_t stream)
{
    const float* x       = (const float*)d_in[0];
    const float* W_fe    = (const float*)d_in[1];
    const float* b_fe    = (const float*)d_in[2];
    const float* gamma1  = (const float*)d_in[3];
    const float* beta1   = (const float*)d_in[4];
    const float* mean1   = (const float*)d_in[5];
    const float* var1    = (const float*)d_in[6];
    const float* kernelw = (const float*)d_in[7];
    const float* reck    = (const float*)d_in[8];
    const float* bias    = (const float*)d_in[9];
    const float* peep_i  = (const float*)d_in[10];
    const float* peep_f  = (const float*)d_in[11];
    const float* peep_o  = (const float*)d_in[12];
    const float* gamma2  = (const float*)d_in[13];
    const float* beta2   = (const float*)d_in[14];
    const float* mean2   = (const float*)d_in[15];
    const float* var2    = (const float*)d_in[16];
    const float* W_out   = (const float*)d_in[17];
    float* out = (float*)d_out;

    char* ws = (char*)d_ws;
    size_t o = 0;
    ushort* wfeT  = (ushort*)(ws + o); o += (size_t)H_ * FP_ * 2;              // 1.64 MB
    ushort* kT2   = (ushort*)(ws + o); o += (size_t)NG_ * H_ * 2;              // 8.39 MB
    ushort* rT2   = (ushort*)(ws + o); o += (size_t)NG_ * H_ * 2;              // 8.39 MB
    ushort* xbf_c = (ushort*)(ws + o); o += (size_t)MC_ * FP_ * 2;             // 6.55 MB
    ushort* feat_c= (ushort*)(ws + o); o += (size_t)MC_ * H_ * 2;              // 8.39 MB
    ushort* zx_c  = (ushort*)(ws + o); o += (size_t)MC_ * NG_ * 2;             // 33.55 MB
    ushort* h_hist= (ushort*)(ws + o); o += (size_t)(TC_ + 1) * B_ * H_ * 2;   // 8.91 MB
    float*  c_buf = (float*)(ws + o);  o += (size_t)B_ * H_ * 4;               // 1.05 MB
    float*  sc1   = (float*)(ws + o);  o += 4096;
    float*  sh1   = (float*)(ws + o);  o += 4096;
    float*  sc2   = (float*)(ws + o);  o += 4096;
    float*  sh2   = (float*)(ws + o);  o += 4096;
    ushort* woutT = (ushort*)(ws + o); o += 16 * H_ * 2;
    unsigned* bar = (unsigned*)(ws + o); o += 256;
    // total ~77 MB

    prep_params<<<dim3(B_ * H_ / 256), dim3(256), 0, stream>>>(
        gamma1, beta1, mean1, var1, gamma2, beta2, mean2, var2, W_out,
        sc1, sh1, sc2, sh2, woutT, c_buf, h_hist, bar);

    transpose_f32_to_bf16<<<dim3(32, 25), dim3(256), 0, stream>>>(W_fe, wfeT, F_, H_, FP_);
    transpose_perm_bf16<<<dim3(128, 32), dim3(256), 0, stream>>>(kernelw, kT2);
    transpose_perm_bf16<<<dim3(128, 32), dim3(256), 0, stream>>>(reck, rT2);

    for (int ci = 0; ci < T_ / TC_; ++ci) {
        int t0 = ci * TC_;
        convert_x<<<dim3(MC_ * FP_ / 8 / 256), dim3(256), 0, stream>>>(x, xbf_c, t0);
        gemm1_c<<<dim3(H_ / 128, MC_ / 128), dim3(256), 0, stream>>>(
            xbf_c, wfeT, b_fe, sc1, sh1, feat_c);
        gemm2_c<<<dim3(NG_ / 128, MC_ / 128), dim3(256), 0, stream>>>(feat_c, kT2, zx_c);
        lstm_chunk<<<dim3(128), dim3(512), 0, stream>>>(
            h_hist, c_buf, rT2, zx_c, bias, peep_i, peep_f, peep_o, bar, ci);
        final_chunk<<<dim3(MC_ / 128), dim3(256), 0, stream>>>(
            h_hist, woutT, sc2, sh2, out, t0);
    }
}

// Round 7
// 6389.534 us; speedup vs baseline: 1.9578x; 1.5596x over previous
//
#include <hip/hip_runtime.h>

#define B_ 256
#define T_ 128
#define F_ 784
#define FP_ 800          // F padded to multiple of 32
#define H_ 1024
#define NG_ 4096         // 4*H
#define C_ 10
#define TC_ 16           // time-chunk length
#define MC_ (B_ * TC_)   // rows per chunk = 4096
#define BN_EPS 1e-3f

typedef short s16x8 __attribute__((ext_vector_type(8)));
typedef float f32x4 __attribute__((ext_vector_type(4)));
typedef unsigned long long u64;

__device__ __forceinline__ ushort f2bf(float f) {
    union { float f; unsigned u; } v; v.f = f;
    unsigned r = v.u + 0x7FFFu + ((v.u >> 16) & 1u);
    return (ushort)(r >> 16);
}
__device__ __forceinline__ float bf2f(ushort h) {
    union { unsigned u; float f; } v; v.u = ((unsigned)h) << 16;
    return v.f;
}
__device__ __forceinline__ float sigm(float x) {
    return 1.0f / (1.0f + __expf(-x));
}
__device__ __forceinline__ float fast_tanh(float x) {
    x = fminf(15.0f, fmaxf(-15.0f, x));
    float e = __expf(2.0f * x);
    return (e - 1.0f) / (e + 1.0f);
}

// ---------------- prep: BN scale/shift, W_out^T bf16, zero state, zero barrier ----------
__global__ __launch_bounds__(256) void prep_params(
    const float* __restrict__ gamma1, const float* __restrict__ beta1,
    const float* __restrict__ mean1, const float* __restrict__ var1,
    const float* __restrict__ gamma2, const float* __restrict__ beta2,
    const float* __restrict__ mean2, const float* __restrict__ var2,
    const float* __restrict__ W_out,
    float* __restrict__ sc1, float* __restrict__ sh1,
    float* __restrict__ sc2, float* __restrict__ sh2,
    ushort* __restrict__ woutT, float* __restrict__ c_buf, ushort* __restrict__ h_hist,
    unsigned* __restrict__ bar)
{
    int idx = blockIdx.x * 256 + threadIdx.x;
    if (idx == 0) *bar = 0u;
    if (idx < B_ * H_) { c_buf[idx] = 0.0f; h_hist[idx] = 0; }  // h slot 0 = h_{-1} = 0
    if (idx < H_) {
        float s1 = gamma1[idx] * rsqrtf(var1[idx] + BN_EPS);
        sc1[idx] = s1; sh1[idx] = beta1[idx] - mean1[idx] * s1;
        float s2 = gamma2[idx] * rsqrtf(var2[idx] + BN_EPS);
        sc2[idx] = s2; sh2[idx] = beta2[idx] - mean2[idx] * s2;
    }
    if (idx < 16 * H_) {
        int n = idx >> 10, k = idx & (H_ - 1);
        woutT[idx] = (n < C_) ? f2bf(W_out[k * C_ + n]) : (ushort)0;
    }
}

// ---------------- generic f32 (K,N) -> bf16 (N,Kpad) transpose, zero-padded ----------------
__global__ __launch_bounds__(256) void transpose_f32_to_bf16(
    const float* __restrict__ src, ushort* __restrict__ dst, int K, int N, int Kpad)
{
    __shared__ float tile[32][33];
    int tx = threadIdx.x & 31, ty = threadIdx.x >> 5;
    int bx = blockIdx.x, by = blockIdx.y;
    int col = bx * 32 + tx;
    for (int l = 0; l < 4; ++l) {
        int row = by * 32 + ty + l * 8;
        tile[ty + l * 8][tx] = (row < K && col < N) ? src[(long)row * N + col] : 0.0f;
    }
    __syncthreads();
    for (int l = 0; l < 4; ++l) {
        int n = bx * 32 + ty + l * 8;
        int k = by * 32 + tx;
        if (n < N && k < Kpad) dst[(long)n * Kpad + k] = f2bf(tile[tx][ty + l * 8]);
    }
}

// ---- same, but output rows gate-packed: src col n = g*H + u  ->  dst row n2 = u*4 + g ----
__global__ __launch_bounds__(256) void transpose_perm_bf16(
    const float* __restrict__ src, ushort* __restrict__ dst)   // K=H_, N=NG_, Kpad=H_
{
    __shared__ float tile[32][33];
    int tx = threadIdx.x & 31, ty = threadIdx.x >> 5;
    int bx = blockIdx.x, by = blockIdx.y;
    int col = bx * 32 + tx;
    for (int l = 0; l < 4; ++l) {
        int row = by * 32 + ty + l * 8;
        tile[ty + l * 8][tx] = (row < H_) ? src[(long)row * NG_ + col] : 0.0f;
    }
    __syncthreads();
    for (int l = 0; l < 4; ++l) {
        int n = bx * 32 + ty + l * 8;       // original col: g*H + u
        int k = by * 32 + tx;
        int n2 = (n & (H_ - 1)) * 4 + (n >> 10);
        dst[(long)n2 * H_ + k] = f2bf(tile[tx][ty + l * 8]);
    }
}

// ---------------- x chunk -> bf16, chunk-row order (tl*B+b), padded K to 800 ----------------
__global__ __launch_bounds__(256) void convert_x(
    const float* __restrict__ x, ushort* __restrict__ xbf, int t0)
{
    int idx = blockIdx.x * 256 + threadIdx.x;
    int m = idx / 100;
    int kc = idx - m * 100;
    int b = m & (B_ - 1), tl = m >> 8;
    int k = kc * 8;
    ushort o[8];
    if (k < F_) {
        const float* src = x + ((long)b * T_ + t0 + tl) * F_ + k;
        float4 v0 = *(const float4*)src, v1 = *(const float4*)(src + 4);
        o[0]=f2bf(v0.x); o[1]=f2bf(v0.y); o[2]=f2bf(v0.z); o[3]=f2bf(v0.w);
        o[4]=f2bf(v1.x); o[5]=f2bf(v1.y); o[6]=f2bf(v1.z); o[7]=f2bf(v1.w);
    } else {
        for (int i = 0; i < 8; ++i) o[i] = 0;
    }
    *(uint4*)(xbf + (long)m * FP_ + k) = *(uint4*)o;
}

// ---------------- GEMM1 (per chunk, pure bf16): feat = tanh(BN(tanh(xbf @ W_fe + b))) ------
__global__ __launch_bounds__(256) void gemm1_c(
    const ushort* __restrict__ xbf, const ushort* __restrict__ wfeT,
    const float* __restrict__ b_fe, const float* __restrict__ sc1, const float* __restrict__ sh1,
    ushort* __restrict__ feat_c)
{
    __shared__ __align__(16) ushort As[128 * 40];
    __shared__ __align__(16) ushort Bs[128 * 40];
    int tid = threadIdx.x;
    int m0 = blockIdx.y * 128, n0 = blockIdx.x * 128;
    int wave = tid >> 6, lane = tid & 63;
    int wm = wave >> 1, wn = wave & 1;
    int l15 = lane & 15, quad = lane >> 4;

    f32x4 zero = {0.f, 0.f, 0.f, 0.f};
    f32x4 acc[4][4];
    for (int i = 0; i < 4; i++) for (int j = 0; j < 4; j++) acc[i][j] = zero;

    for (int kk = 0; kk < FP_ / 32; ++kk) {
        int kb = kk * 32;
        for (int c = tid; c < 1024; c += 256) {
            if (c < 512) {
                int row = c >> 2, ch = c & 3;
                *(uint4*)&As[row * 40 + ch * 8] =
                    *(const uint4*)(xbf + (long)(m0 + row) * FP_ + kb + ch * 8);
            } else {
                int cb = c - 512;
                int row = cb >> 2, ch = cb & 3;
                *(uint4*)&Bs[row * 40 + ch * 8] =
                    *(const uint4*)(wfeT + (long)(n0 + row) * FP_ + kb + ch * 8);
            }
        }
        __syncthreads();
        s16x8 af[4], bfr[4];
        for (int i = 0; i < 4; i++) af[i]  = *(const s16x8*)&As[(wm * 64 + i * 16 + l15) * 40 + quad * 8];
        for (int j = 0; j < 4; j++) bfr[j] = *(const s16x8*)&Bs[(wn * 64 + j * 16 + l15) * 40 + quad * 8];
        for (int i = 0; i < 4; i++)
            for (int j = 0; j < 4; j++)
                acc[i][j] = __builtin_amdgcn_mfma_f32_16x16x32_bf16(af[i], bfr[j], acc[i][j], 0, 0, 0);
        __syncthreads();
    }
    for (int j = 0; j < 4; j++) {
        int n_g = n0 + wn * 64 + j * 16 + l15;
        float bia = b_fe[n_g], s = sc1[n_g], sh = sh1[n_g];
        for (int i = 0; i < 4; i++) {
            int mb = m0 + wm * 64 + i * 16 + quad * 4;
            for (int r = 0; r < 4; r++) {
                float v = fast_tanh(acc[i][j][r] + bia);
                v = fast_tanh(v * s + sh);
                feat_c[(long)(mb + r) * H_ + n_g] = f2bf(v);
            }
        }
    }
}

// ---------------- GEMM2 (per chunk): zx_c = feat_c @ kernel(packed) -> bf16 (MC_, 4H) ------
__global__ __launch_bounds__(256) void gemm2_c(
    const ushort* __restrict__ feat_c, const ushort* __restrict__ kT2,
    ushort* __restrict__ zx_c)
{
    __shared__ __align__(16) ushort As[128 * 40];
    __shared__ __align__(16) ushort Bs[128 * 40];
    int tid = threadIdx.x;
    int m0 = blockIdx.y * 128, n0 = blockIdx.x * 128;
    int wave = tid >> 6, lane = tid & 63;
    int wm = wave >> 1, wn = wave & 1;
    int l15 = lane & 15, quad = lane >> 4;

    f32x4 zero = {0.f, 0.f, 0.f, 0.f};
    f32x4 acc[4][4];
    for (int i = 0; i < 4; i++) for (int j = 0; j < 4; j++) acc[i][j] = zero;

    for (int kk = 0; kk < H_ / 32; ++kk) {
        int kb = kk * 32;
        for (int c = tid; c < 1024; c += 256) {
            if (c < 512) {
                int row = c >> 2, ch = c & 3;
                *(uint4*)&As[row * 40 + ch * 8] =
                    *(const uint4*)(feat_c + (long)(m0 + row) * H_ + kb + ch * 8);
            } else {
                int cb = c - 512;
                int row = cb >> 2, ch = cb & 3;
                *(uint4*)&Bs[row * 40 + ch * 8] =
                    *(const uint4*)(kT2 + (long)(n0 + row) * H_ + kb + ch * 8);
            }
        }
        __syncthreads();
        s16x8 af[4], bfr[4];
        for (int i = 0; i < 4; i++) af[i]  = *(const s16x8*)&As[(wm * 64 + i * 16 + l15) * 40 + quad * 8];
        for (int j = 0; j < 4; j++) bfr[j] = *(const s16x8*)&Bs[(wn * 64 + j * 16 + l15) * 40 + quad * 8];
        for (int i = 0; i < 4; i++)
            for (int j = 0; j < 4; j++)
                acc[i][j] = __builtin_amdgcn_mfma_f32_16x16x32_bf16(af[i], bfr[j], acc[i][j], 0, 0, 0);
        __syncthreads();
    }
    for (int j = 0; j < 4; j++) {
        int n_g = n0 + wn * 64 + j * 16 + l15;
        for (int i = 0; i < 4; i++) {
            int mb = m0 + wm * 64 + i * 16 + quad * 4;
            for (int r = 0; r < 4; r++)
                zx_c[(long)(mb + r) * NG_ + n_g] = f2bf(acc[i][j][r]);
        }
    }
}

// ---------------- persistent LSTM chunk v4: wide plain h loads, write-through h stores ------
// 128 blocks x 512 thr, 8 units/block; R strip in LDS for all 16 steps.
// h STORES: agent-scope 8B atomic stores -> execute at the memory-side coherence point,
//   leaving no dirty line in any XCD L2.
// h LOADS: plain coalesced uint4 loads. Safe: within this launch every h-slot address is
//   read only after the grid barrier following its (write-through) store, and the launch
//   boundary invalidated stale lines -> a reader L2 can never hold a stale copy; first
//   reader per XCD misses to IF$, the rest hit local L2 (traffic 64MB/step -> ~4MB/step).
#define RS2 1032   // LDS row stride (ushorts): 16B-aligned rows
__global__ __launch_bounds__(512, 1) void lstm_chunk(
    ushort* __restrict__ h_hist, float* __restrict__ c_buf,
    const ushort* __restrict__ rT2, const ushort* __restrict__ zx_c,
    const float* __restrict__ bias, const float* __restrict__ pi,
    const float* __restrict__ pf, const float* __restrict__ po,
    unsigned* __restrict__ bar, int ci)
{
    __shared__ ushort Rs[32 * RS2];      // ~66 KB
    __shared__ float zbuf[32][257];      // ~33 KB
    int tid = threadIdx.x;
    int ub = blockIdx.x * 8;             // first hidden unit owned by this block
    int wave = tid >> 6, lane = tid & 63;
    int wm = wave >> 1, wn = wave & 1;   // 4 m-groups x 2 n-groups
    int l15 = lane & 15, quad = lane >> 4;

    // stage R strip: packed rows [ub*4, ub*4+32) x 1024 k
    for (int c = tid; c < 4096; c += 512) {
        int row = c >> 7, kc = c & 127;
        *(uint4*)&Rs[row * RS2 + kc * 8] =
            *(const uint4*)(rT2 + (long)(ub * 4 + row) * H_ + kc * 8);
    }

    int b = tid & 255, half = tid >> 8;  // cell-update identity
    float cst[4];
    *(float4*)cst = *(const float4*)(c_buf + (long)b * H_ + ub + half * 4);
    float bi4[4], bf4[4], bc4[4], bo4[4], pI[4], pF[4], pO[4];
    for (int u = 0; u < 4; ++u) {
        int ug = ub + half * 4 + u;
        bi4[u] = bias[ug];          bf4[u] = bias[H_ + ug];
        bc4[u] = bias[2 * H_ + ug]; bo4[u] = bias[3 * H_ + ug];
        pI[u] = pi[ug]; pF[u] = pf[ug]; pO[u] = po[ug];
    }
    __syncthreads();

    for (int tl = 0; tl < TC_; ++tl) {
        const ushort* hsrc = h_hist +
            (size_t)((tl == 0) ? (ci == 0 ? 0 : TC_) : tl) * (B_ * H_);

        f32x4 acc[4];
        #pragma unroll
        for (int mt = 0; mt < 4; ++mt) acc[mt] = (f32x4){0.f, 0.f, 0.f, 0.f};

        for (int kk = 0; kk < 32; ++kk) {
            s16x8 bfr = *(const s16x8*)&Rs[(wn * 16 + l15) * RS2 + kk * 32 + quad * 8];
            const ushort* hk = hsrc + (size_t)(wm * 64 + l15) * H_ + kk * 32 + quad * 8;
            #pragma unroll
            for (int mt = 0; mt < 4; ++mt) {
                s16x8 af = *(const s16x8*)(hk + (size_t)mt * 16 * H_);   // plain 16B load
                acc[mt] = __builtin_amdgcn_mfma_f32_16x16x32_bf16(af, bfr, acc[mt], 0, 0, 0);
            }
        }

        // z -> LDS, col-major
        #pragma unroll
        for (int mt = 0; mt < 4; ++mt)
            #pragma unroll
            for (int r = 0; r < 4; ++r)
                zbuf[wn * 16 + l15][wm * 64 + mt * 16 + quad * 4 + r] = acc[mt][r];
        __syncthreads();

        // cell update: zx gate-packed -> one contiguous 32B read per thread
        const ushort* zr = zx_c + ((size_t)tl * B_ + b) * NG_ + ub * 4 + half * 16;
        ushort zv[16];
        *(uint4*)&zv[0] = *(const uint4*)zr;
        *(uint4*)&zv[8] = *(const uint4*)(zr + 8);
        ushort hnew[4];
        #pragma unroll
        for (int u = 0; u < 4; ++u) {
            int cb2 = half * 16 + u * 4;
            float zi = zbuf[cb2 + 0][b] + bi4[u] + bf2f(zv[u * 4 + 0]);
            float zf = zbuf[cb2 + 1][b] + bf4[u] + bf2f(zv[u * 4 + 1]);
            float zc = zbuf[cb2 + 2][b] + bc4[u] + bf2f(zv[u * 4 + 2]);
            float zo = zbuf[cb2 + 3][b] + bo4[u] + bf2f(zv[u * 4 + 3]);
            float co = cst[u];
            float ig = sigm(zi + co * pI[u]);
            float fg = sigm(zf + co * pF[u]);
            float cn = fg * co + ig * fast_tanh(zc);
            float og = sigm(zo + cn * pO[u]);
            cst[u] = cn;
            hnew[u] = f2bf(og * fast_tanh(cn));
        }
        union { ushort s[4]; u64 q; } hv;
        hv.s[0] = hnew[0]; hv.s[1] = hnew[1]; hv.s[2] = hnew[2]; hv.s[3] = hnew[3];
        __hip_atomic_store(
            (u64*)(h_hist + (size_t)(tl + 1) * (B_ * H_) + (size_t)b * H_ + ub + half * 4),
            hv.q, __ATOMIC_RELAXED, __HIP_MEMORY_SCOPE_AGENT);

        // grid barrier: syncthreads drains vmcnt (h stores complete at coherence point),
        // then RMW arrival + read-only poll. No fences.
        __syncthreads();
        if (tid == 0) {
            unsigned target = (unsigned)(ci * TC_ + tl + 1) * 128u;
            __hip_atomic_fetch_add(bar, 1u, __ATOMIC_RELAXED, __HIP_MEMORY_SCOPE_AGENT);
            while (__hip_atomic_load(bar, __ATOMIC_RELAXED, __HIP_MEMORY_SCOPE_AGENT) < target)
                __builtin_amdgcn_s_sleep(2);
        }
        __syncthreads();
    }
    *(float4*)(c_buf + (long)b * H_ + ub + half * 4) = *(float4*)cst;
}

// ---------------- final (per chunk): out = tanh(BN(h)) @ W_out  (N padded 10->16) ----------
__global__ __launch_bounds__(256) void final_chunk(
    const ushort* __restrict__ h_hist, const ushort* __restrict__ woutT,
    const float* __restrict__ sc2, const float* __restrict__ sh2,
    float* __restrict__ out, int t0)
{
    __shared__ __align__(16) ushort As[128 * 40];
    __shared__ __align__(16) ushort Bs[16 * 40];
    int tid = threadIdx.x;
    long r0 = (long)blockIdx.x * 128;
    const ushort* hbase = h_hist + (long)B_ * H_ + r0 * H_;   // slot 1 onward
    int wave = tid >> 6, lane = tid & 63;
    int l15 = lane & 15, quad = lane >> 4;

    f32x4 zero = {0.f, 0.f, 0.f, 0.f};
    f32x4 acc[2]; acc[0] = zero; acc[1] = zero;

    for (int kk = 0; kk < H_ / 32; ++kk) {
        int kb = kk * 32;
        for (int c = tid; c < 512; c += 256) {
            int row = c >> 2, ch = c & 3;
            int k = kb + ch * 8;
            union { uint4 u4; ushort s[8]; } in, ov;
            in.u4 = *(const uint4*)(hbase + (long)row * H_ + k);
            float4 sa = *(const float4*)(sc2 + k), sb = *(const float4*)(sc2 + k + 4);
            float4 ba = *(const float4*)(sh2 + k), bb = *(const float4*)(sh2 + k + 4);
            ov.s[0] = f2bf(fast_tanh(bf2f(in.s[0]) * sa.x + ba.x));
            ov.s[1] = f2bf(fast_tanh(bf2f(in.s[1]) * sa.y + ba.y));
            ov.s[2] = f2bf(fast_tanh(bf2f(in.s[2]) * sa.z + ba.z));
            ov.s[3] = f2bf(fast_tanh(bf2f(in.s[3]) * sa.w + ba.w));
            ov.s[4] = f2bf(fast_tanh(bf2f(in.s[4]) * sb.x + bb.x));
            ov.s[5] = f2bf(fast_tanh(bf2f(in.s[5]) * sb.y + bb.y));
            ov.s[6] = f2bf(fast_tanh(bf2f(in.s[6]) * sb.z + bb.z));
            ov.s[7] = f2bf(fast_tanh(bf2f(in.s[7]) * sb.w + bb.w));
            *(uint4*)&As[row * 40 + ch * 8] = ov.u4;
        }
        if (tid < 64) {
            int row = tid >> 2, ch = tid & 3;
            *(uint4*)&Bs[row * 40 + ch * 8] = *(const uint4*)(woutT + row * H_ + kb + ch * 8);
        }
        __syncthreads();
        s16x8 bfr = *(const s16x8*)&Bs[l15 * 40 + quad * 8];
        for (int i = 0; i < 2; i++) {
            s16x8 af = *(const s16x8*)&As[(wave * 32 + i * 16 + l15) * 40 + quad * 8];
            acc[i] = __builtin_amdgcn_mfma_f32_16x16x32_bf16(af, bfr, acc[i], 0, 0, 0);
        }
        __syncthreads();
    }
    if (l15 < C_) {
        for (int i = 0; i < 2; i++)
            for (int r = 0; r < 4; r++) {
                long rg = r0 + wave * 32 + i * 16 + quad * 4 + r;  // = tl*B + b
                int tl = (int)(rg >> 8);
                int b  = (int)(rg & (B_ - 1));
                out[((long)b * T_ + t0 + tl) * C_ + l15] = acc[i][r];
            }
    }
}

extern "C" void kernel_launch(void* const* d_in, const int* in_sizes, int n_in,
                              void* d_out, int out_size, void* d_ws, size_t ws_size,
                              hipStream_t stream)
{
    const float* x       = (const float*)d_in[0];
    const float* W_fe    = (const float*)d_in[1];
    const float* b_fe    = (const float*)d_in[2];
    const float* gamma1  = (const float*)d_in[3];
    const float* beta1   = (const float*)d_in[4];
    const float* mean1   = (const float*)d_in[5];
    const float* var1    = (const float*)d_in[6];
    const float* kernelw = (const float*)d_in[7];
    const float* reck    = (const float*)d_in[8];
    const float* bias    = (const float*)d_in[9];
    const float* peep_i  = (const float*)d_in[10];
    const float* peep_f  = (const float*)d_in[11];
    const float* peep_o  = (const float*)d_in[12];
    const float* gamma2  = (const float*)d_in[13];
    const float* beta2   = (const float*)d_in[14];
    const float* mean2   = (const float*)d_in[15];
    const float* var2    = (const float*)d_in[16];
    const float* W_out   = (const float*)d_in[17];
    float* out = (float*)d_out;

    char* ws = (char*)d_ws;
    size_t o = 0;
    ushort* wfeT  = (ushort*)(ws + o); o += (size_t)H_ * FP_ * 2;              // 1.64 MB
    ushort* kT2   = (ushort*)(ws + o); o += (size_t)NG_ * H_ * 2;              // 8.39 MB
    ushort* rT2   = (ushort*)(ws + o); o += (size_t)NG_ * H_ * 2;              // 8.39 MB
    ushort* xbf_c = (ushort*)(ws + o); o += (size_t)MC_ * FP_ * 2;             // 6.55 MB
    ushort* feat_c= (ushort*)(ws + o); o += (size_t)MC_ * H_ * 2;              // 8.39 MB
    ushort* zx_c  = (ushort*)(ws + o); o += (size_t)MC_ * NG_ * 2;             // 33.55 MB
    ushort* h_hist= (ushort*)(ws + o); o += (size_t)(TC_ + 1) * B_ * H_ * 2;   // 8.91 MB
    float*  c_buf = (float*)(ws + o);  o += (size_t)B_ * H_ * 4;               // 1.05 MB
    float*  sc1   = (float*)(ws + o);  o += 4096;
    float*  sh1   = (float*)(ws + o);  o += 4096;
    float*  sc2   = (float*)(ws + o);  o += 4096;
    float*  sh2   = (float*)(ws + o);  o += 4096;
    ushort* woutT = (ushort*)(ws + o); o += 16 * H_ * 2;
    unsigned* bar = (unsigned*)(ws + o); o += 256;
    // total ~77 MB

    prep_params<<<dim3(B_ * H_ / 256), dim3(256), 0, stream>>>(
        gamma1, beta1, mean1, var1, gamma2, beta2, mean2, var2, W_out,
        sc1, sh1, sc2, sh2, woutT, c_buf, h_hist, bar);

    transpose_f32_to_bf16<<<dim3(32, 25), dim3(256), 0, stream>>>(W_fe, wfeT, F_, H_, FP_);
    transpose_perm_bf16<<<dim3(128, 32), dim3(256), 0, stream>>>(kernelw, kT2);
    transpose_perm_bf16<<<dim3(128, 32), dim3(256), 0, stream>>>(reck, rT2);

    for (int ci = 0; ci < T_ / TC_; ++ci) {
        int t0 = ci * TC_;
        convert_x<<<dim3(MC_ * FP_ / 8 / 256), dim3(256), 0, stream>>>(x, xbf_c, t0);
        gemm1_c<<<dim3(H_ / 128, MC_ / 128), dim3(256), 0, stream>>>(
            xbf_c, wfeT, b_fe, sc1, sh1, feat_c);
        gemm2_c<<<dim3(NG_ / 128, MC_ / 128), dim3(256), 0, stream>>>(feat_c, kT2, zx_c);
        lstm_chunk<<<dim3(128), dim3(512), 0, stream>>>(
            h_hist, c_buf, rT2, zx_c, bias, peep_i, peep_f, peep_o, bar, ci);
        final_chunk<<<dim3(MC_ / 128), dim3(256), 0, stream>>>(
            h_hist, woutT, sc2, sh2, out, t0);
    }
}

// Round 8
// 4685.125 us; speedup vs baseline: 2.6700x; 1.3638x over previous
//
#include <hip/hip_runtime.h>

#define B_ 256
#define T_ 128
#define F_ 784
#define FP_ 800          // F padded to multiple of 32
#define H_ 1024
#define NG_ 4096         // 4*H
#define C_ 10
#define TC_ 16           // time-chunk length
#define MC_ (B_ * TC_)   // rows per chunk = 4096
#define BN_EPS 1e-3f

typedef short s16x8 __attribute__((ext_vector_type(8)));
typedef float f32x4 __attribute__((ext_vector_type(4)));
typedef unsigned long long u64;

__device__ __forceinline__ ushort f2bf(float f) {
    union { float f; unsigned u; } v; v.f = f;
    unsigned r = v.u + 0x7FFFu + ((v.u >> 16) & 1u);
    return (ushort)(r >> 16);
}
__device__ __forceinline__ float bf2f(ushort h) {
    union { unsigned u; float f; } v; v.u = ((unsigned)h) << 16;
    return v.f;
}
__device__ __forceinline__ float sigm(float x) {
    return 1.0f / (1.0f + __expf(-x));
}
__device__ __forceinline__ float fast_tanh(float x) {
    x = fminf(15.0f, fmaxf(-15.0f, x));
    float e = __expf(2.0f * x);
    return (e - 1.0f) / (e + 1.0f);
}

// ---------------- prep: BN scale/shift, W_out^T bf16, zero state, zero barriers ----------
__global__ __launch_bounds__(256) void prep_params(
    const float* __restrict__ gamma1, const float* __restrict__ beta1,
    const float* __restrict__ mean1, const float* __restrict__ var1,
    const float* __restrict__ gamma2, const float* __restrict__ beta2,
    const float* __restrict__ mean2, const float* __restrict__ var2,
    const float* __restrict__ W_out,
    float* __restrict__ sc1, float* __restrict__ sh1,
    float* __restrict__ sc2, float* __restrict__ sh2,
    ushort* __restrict__ woutT, float* __restrict__ c_buf, ushort* __restrict__ h_hist,
    unsigned* __restrict__ bar)
{
    int idx = blockIdx.x * 256 + threadIdx.x;
    if (idx < 512) bar[idx] = 0u;
    if (idx < B_ * H_) { c_buf[idx] = 0.0f; h_hist[idx] = 0; }  // h slot 0 = h_{-1} = 0
    if (idx < H_) {
        float s1 = gamma1[idx] * rsqrtf(var1[idx] + BN_EPS);
        sc1[idx] = s1; sh1[idx] = beta1[idx] - mean1[idx] * s1;
        float s2 = gamma2[idx] * rsqrtf(var2[idx] + BN_EPS);
        sc2[idx] = s2; sh2[idx] = beta2[idx] - mean2[idx] * s2;
    }
    if (idx < 16 * H_) {
        int n = idx >> 10, k = idx & (H_ - 1);
        woutT[idx] = (n < C_) ? f2bf(W_out[k * C_ + n]) : (ushort)0;
    }
}

// ---------------- generic f32 (K,N) -> bf16 (N,Kpad) transpose, zero-padded ----------------
__global__ __launch_bounds__(256) void transpose_f32_to_bf16(
    const float* __restrict__ src, ushort* __restrict__ dst, int K, int N, int Kpad)
{
    __shared__ float tile[32][33];
    int tx = threadIdx.x & 31, ty = threadIdx.x >> 5;
    int bx = blockIdx.x, by = blockIdx.y;
    int col = bx * 32 + tx;
    for (int l = 0; l < 4; ++l) {
        int row = by * 32 + ty + l * 8;
        tile[ty + l * 8][tx] = (row < K && col < N) ? src[(long)row * N + col] : 0.0f;
    }
    __syncthreads();
    for (int l = 0; l < 4; ++l) {
        int n = bx * 32 + ty + l * 8;
        int k = by * 32 + tx;
        if (n < N && k < Kpad) dst[(long)n * Kpad + k] = f2bf(tile[tx][ty + l * 8]);
    }
}

// ---- same, but output rows gate-packed: src col n = g*H + u  ->  dst row n2 = u*4 + g ----
__global__ __launch_bounds__(256) void transpose_perm_bf16(
    const float* __restrict__ src, ushort* __restrict__ dst)   // K=H_, N=NG_, Kpad=H_
{
    __shared__ float tile[32][33];
    int tx = threadIdx.x & 31, ty = threadIdx.x >> 5;
    int bx = blockIdx.x, by = blockIdx.y;
    int col = bx * 32 + tx;
    for (int l = 0; l < 4; ++l) {
        int row = by * 32 + ty + l * 8;
        tile[ty + l * 8][tx] = (row < H_) ? src[(long)row * NG_ + col] : 0.0f;
    }
    __syncthreads();
    for (int l = 0; l < 4; ++l) {
        int n = bx * 32 + ty + l * 8;       // original col: g*H + u
        int k = by * 32 + tx;
        int n2 = (n & (H_ - 1)) * 4 + (n >> 10);
        dst[(long)n2 * H_ + k] = f2bf(tile[tx][ty + l * 8]);
    }
}

// ---------------- x chunk -> bf16, chunk-row order (tl*B+b), padded K to 800 ----------------
__global__ __launch_bounds__(256) void convert_x(
    const float* __restrict__ x, ushort* __restrict__ xbf, int t0)
{
    int idx = blockIdx.x * 256 + threadIdx.x;
    int m = idx / 100;
    int kc = idx - m * 100;
    int b = m & (B_ - 1), tl = m >> 8;
    int k = kc * 8;
    ushort o[8];
    if (k < F_) {
        const float* src = x + ((long)b * T_ + t0 + tl) * F_ + k;
        float4 v0 = *(const float4*)src, v1 = *(const float4*)(src + 4);
        o[0]=f2bf(v0.x); o[1]=f2bf(v0.y); o[2]=f2bf(v0.z); o[3]=f2bf(v0.w);
        o[4]=f2bf(v1.x); o[5]=f2bf(v1.y); o[6]=f2bf(v1.z); o[7]=f2bf(v1.w);
    } else {
        for (int i = 0; i < 8; ++i) o[i] = 0;
    }
    *(uint4*)(xbf + (long)m * FP_ + k) = *(uint4*)o;
}

// ---------------- GEMM1 (per chunk, pure bf16): feat = tanh(BN(tanh(xbf @ W_fe + b))) ------
__global__ __launch_bounds__(256) void gemm1_c(
    const ushort* __restrict__ xbf, const ushort* __restrict__ wfeT,
    const float* __restrict__ b_fe, const float* __restrict__ sc1, const float* __restrict__ sh1,
    ushort* __restrict__ feat_c)
{
    __shared__ __align__(16) ushort As[128 * 40];
    __shared__ __align__(16) ushort Bs[128 * 40];
    int tid = threadIdx.x;
    int m0 = blockIdx.y * 128, n0 = blockIdx.x * 128;
    int wave = tid >> 6, lane = tid & 63;
    int wm = wave >> 1, wn = wave & 1;
    int l15 = lane & 15, quad = lane >> 4;

    f32x4 zero = {0.f, 0.f, 0.f, 0.f};
    f32x4 acc[4][4];
    for (int i = 0; i < 4; i++) for (int j = 0; j < 4; j++) acc[i][j] = zero;

    for (int kk = 0; kk < FP_ / 32; ++kk) {
        int kb = kk * 32;
        for (int c = tid; c < 1024; c += 256) {
            if (c < 512) {
                int row = c >> 2, ch = c & 3;
                *(uint4*)&As[row * 40 + ch * 8] =
                    *(const uint4*)(xbf + (long)(m0 + row) * FP_ + kb + ch * 8);
            } else {
                int cb = c - 512;
                int row = cb >> 2, ch = cb & 3;
                *(uint4*)&Bs[row * 40 + ch * 8] =
                    *(const uint4*)(wfeT + (long)(n0 + row) * FP_ + kb + ch * 8);
            }
        }
        __syncthreads();
        s16x8 af[4], bfr[4];
        for (int i = 0; i < 4; i++) af[i]  = *(const s16x8*)&As[(wm * 64 + i * 16 + l15) * 40 + quad * 8];
        for (int j = 0; j < 4; j++) bfr[j] = *(const s16x8*)&Bs[(wn * 64 + j * 16 + l15) * 40 + quad * 8];
        for (int i = 0; i < 4; i++)
            for (int j = 0; j < 4; j++)
                acc[i][j] = __builtin_amdgcn_mfma_f32_16x16x32_bf16(af[i], bfr[j], acc[i][j], 0, 0, 0);
        __syncthreads();
    }
    for (int j = 0; j < 4; j++) {
        int n_g = n0 + wn * 64 + j * 16 + l15;
        float bia = b_fe[n_g], s = sc1[n_g], sh = sh1[n_g];
        for (int i = 0; i < 4; i++) {
            int mb = m0 + wm * 64 + i * 16 + quad * 4;
            for (int r = 0; r < 4; r++) {
                float v = fast_tanh(acc[i][j][r] + bia);
                v = fast_tanh(v * s + sh);
                feat_c[(long)(mb + r) * H_ + n_g] = f2bf(v);
            }
        }
    }
}

// ---------------- GEMM2 (per chunk): zx_c = feat_c @ kernel(packed) -> bf16 (MC_, 4H) ------
__global__ __launch_bounds__(256) void gemm2_c(
    const ushort* __restrict__ feat_c, const ushort* __restrict__ kT2,
    ushort* __restrict__ zx_c)
{
    __shared__ __align__(16) ushort As[128 * 40];
    __shared__ __align__(16) ushort Bs[128 * 40];
    int tid = threadIdx.x;
    int m0 = blockIdx.y * 128, n0 = blockIdx.x * 128;
    int wave = tid >> 6, lane = tid & 63;
    int wm = wave >> 1, wn = wave & 1;
    int l15 = lane & 15, quad = lane >> 4;

    f32x4 zero = {0.f, 0.f, 0.f, 0.f};
    f32x4 acc[4][4];
    for (int i = 0; i < 4; i++) for (int j = 0; j < 4; j++) acc[i][j] = zero;

    for (int kk = 0; kk < H_ / 32; ++kk) {
        int kb = kk * 32;
        for (int c = tid; c < 1024; c += 256) {
            if (c < 512) {
                int row = c >> 2, ch = c & 3;
                *(uint4*)&As[row * 40 + ch * 8] =
                    *(const uint4*)(feat_c + (long)(m0 + row) * H_ + kb + ch * 8);
            } else {
                int cb = c - 512;
                int row = cb >> 2, ch = cb & 3;
                *(uint4*)&Bs[row * 40 + ch * 8] =
                    *(const uint4*)(kT2 + (long)(n0 + row) * H_ + kb + ch * 8);
            }
        }
        __syncthreads();
        s16x8 af[4], bfr[4];
        for (int i = 0; i < 4; i++) af[i]  = *(const s16x8*)&As[(wm * 64 + i * 16 + l15) * 40 + quad * 8];
        for (int j = 0; j < 4; j++) bfr[j] = *(const s16x8*)&Bs[(wn * 64 + j * 16 + l15) * 40 + quad * 8];
        for (int i = 0; i < 4; i++)
            for (int j = 0; j < 4; j++)
                acc[i][j] = __builtin_amdgcn_mfma_f32_16x16x32_bf16(af[i], bfr[j], acc[i][j], 0, 0, 0);
        __syncthreads();
    }
    for (int j = 0; j < 4; j++) {
        int n_g = n0 + wn * 64 + j * 16 + l15;
        for (int i = 0; i < 4; i++) {
            int mb = m0 + wm * 64 + i * 16 + quad * 4;
            for (int r = 0; r < 4; r++)
                zx_c[(long)(mb + r) * NG_ + n_g] = f2bf(acc[i][j][r]);
        }
    }
}

// ---------------- persistent LSTM chunk v5: 2 independent batch domains, 256 blocks ---------
// Batch rows 0-127 and 128-255 never interact (recurrence couples only units within a row)
// -> 2 barrier domains of 128 blocks each. Block = (domain, 8 units); M=128 rows/block
// halves per-CU h-request work vs v4 and uses all 256 CUs (82.5 KB LDS -> 1 block/CU).
// Barrier: two-level (8 group counters x 16 blocks + root) to cut same-line RMW serialization.
#define RS2 1032   // LDS row stride (ushorts): 16B-aligned rows
__global__ __launch_bounds__(512, 1) void lstm_chunk(
    ushort* __restrict__ h_hist, float* __restrict__ c_buf,
    const ushort* __restrict__ rT2, const ushort* __restrict__ zx_c,
    const float* __restrict__ bias, const float* __restrict__ pi,
    const float* __restrict__ pf, const float* __restrict__ po,
    unsigned* __restrict__ bar, int ci)
{
    __shared__ ushort Rs[32 * RS2];      // 66 KB
    __shared__ float zbuf[32][129];      // 16.5 KB
    int tid = threadIdx.x;
    int dom = blockIdx.x & 1;            // batch-domain: rows dom*128 ..
    int nb  = blockIdx.x >> 1;           // 0..127 unit-block
    int ub  = nb * 8;                    // first hidden unit owned
    int m0  = dom * 128;
    unsigned* grpCnt  = bar + ((dom * 8) + (nb >> 4)) * 16;  // 16 lines, 64B apart
    unsigned* rootCnt = bar + 256 + dom * 16;

    int wave = tid >> 6, lane = tid & 63;
    int wm = wave >> 1, wn = wave & 1;   // 4 m-groups (32 rows) x 2 n-groups (16 cols)
    int l15 = lane & 15, quad = lane >> 4;

    // stage R strip: packed rows [ub*4, ub*4+32) x 1024 k
    for (int c = tid; c < 4096; c += 512) {
        int row = c >> 7, kc = c & 127;
        *(uint4*)&Rs[row * RS2 + kc * 8] =
            *(const uint4*)(rT2 + (long)(ub * 4 + row) * H_ + kc * 8);
    }

    int b2 = tid & 127, seg = tid >> 7;  // cell identity: local row b2, units seg*2..seg*2+1
    int gr = m0 + b2;                    // global batch row
    float cst[2];
    *(float2*)cst = *(const float2*)(c_buf + (long)gr * H_ + ub + seg * 2);
    float bi2[2], bff[2], bc2[2], bo2[2], pI[2], pF[2], pO[2];
    for (int u = 0; u < 2; ++u) {
        int ug = ub + seg * 2 + u;
        bi2[u] = bias[ug];          bff[u] = bias[H_ + ug];
        bc2[u] = bias[2 * H_ + ug]; bo2[u] = bias[3 * H_ + ug];
        pI[u] = pi[ug]; pF[u] = pf[ug]; pO[u] = po[ug];
    }
    __syncthreads();

    for (int tl = 0; tl < TC_; ++tl) {
        const ushort* hsrc = h_hist +
            (size_t)((tl == 0) ? (ci == 0 ? 0 : TC_) : tl) * (B_ * H_) + (size_t)m0 * H_;

        f32x4 acc0 = {0.f, 0.f, 0.f, 0.f}, acc1 = {0.f, 0.f, 0.f, 0.f};
        const ushort* hrow = hsrc + (size_t)(wm * 32 + l15) * H_ + quad * 8;
        #pragma unroll 4
        for (int kk = 0; kk < 32; ++kk) {
            s16x8 bfr = *(const s16x8*)&Rs[(wn * 16 + l15) * RS2 + kk * 32 + quad * 8];
            s16x8 a0 = *(const s16x8*)(hrow + kk * 32);
            s16x8 a1 = *(const s16x8*)(hrow + (size_t)16 * H_ + kk * 32);
            acc0 = __builtin_amdgcn_mfma_f32_16x16x32_bf16(a0, bfr, acc0, 0, 0, 0);
            acc1 = __builtin_amdgcn_mfma_f32_16x16x32_bf16(a1, bfr, acc1, 0, 0, 0);
        }

        // z -> LDS, col-major: zbuf[gatecol][local row]
        #pragma unroll
        for (int r = 0; r < 4; ++r)
            zbuf[wn * 16 + l15][wm * 32 + quad * 4 + r] = acc0[r];
        #pragma unroll
        for (int r = 0; r < 4; ++r)
            zbuf[wn * 16 + l15][wm * 32 + 16 + quad * 4 + r] = acc1[r];
        __syncthreads();

        // cell update: 2 units/thread; zx gate-packed -> one contiguous 16B read
        const ushort* zr = zx_c + ((size_t)tl * B_ + gr) * NG_ + (ub + seg * 2) * 4;
        union { uint4 u4; ushort s[8]; } zv; zv.u4 = *(const uint4*)zr;
        ushort hnew[2];
        #pragma unroll
        for (int u = 0; u < 2; ++u) {
            int cb2 = (seg * 2 + u) * 4;
            float zi = zbuf[cb2 + 0][b2] + bi2[u] + bf2f(zv.s[u * 4 + 0]);
            float zf = zbuf[cb2 + 1][b2] + bff[u] + bf2f(zv.s[u * 4 + 1]);
            float zc = zbuf[cb2 + 2][b2] + bc2[u] + bf2f(zv.s[u * 4 + 2]);
            float zo = zbuf[cb2 + 3][b2] + bo2[u] + bf2f(zv.s[u * 4 + 3]);
            float co = cst[u];
            float ig = sigm(zi + co * pI[u]);
            float fg = sigm(zf + co * pF[u]);
            float cn = fg * co + ig * fast_tanh(zc);
            float og = sigm(zo + cn * pO[u]);
            cst[u] = cn;
            hnew[u] = f2bf(og * fast_tanh(cn));
        }
        union { ushort s[2]; unsigned w; } hv;
        hv.s[0] = hnew[0]; hv.s[1] = hnew[1];
        __hip_atomic_store(
            (unsigned*)(h_hist + (size_t)(tl + 1) * (B_ * H_) + (size_t)gr * H_ + ub + seg * 2),
            hv.w, __ATOMIC_RELAXED, __HIP_MEMORY_SCOPE_AGENT);

        // two-level grid barrier (per domain), no fences: syncthreads drains vmcnt first
        __syncthreads();
        if (tid == 0) {
            unsigned sg = (unsigned)(ci * TC_ + tl);
            unsigned old = __hip_atomic_fetch_add(grpCnt, 1u,
                                __ATOMIC_RELAXED, __HIP_MEMORY_SCOPE_AGENT);
            if (old == sg * 16u + 15u)    // last of this group's 16 blocks this step
                __hip_atomic_fetch_add(rootCnt, 1u,
                                __ATOMIC_RELAXED, __HIP_MEMORY_SCOPE_AGENT);
            unsigned tgt = (sg + 1u) * 8u;
            while (__hip_atomic_load(rootCnt, __ATOMIC_RELAXED, __HIP_MEMORY_SCOPE_AGENT) < tgt)
                __builtin_amdgcn_s_sleep(2);
        }
        __syncthreads();
    }
    *(float2*)(c_buf + (long)gr * H_ + ub + seg * 2) = *(float2*)cst;
}

// ---------------- final (per chunk): out = tanh(BN(h)) @ W_out  (N padded 10->16) ----------
__global__ __launch_bounds__(256) void final_chunk(
    const ushort* __restrict__ h_hist, const ushort* __restrict__ woutT,
    const float* __restrict__ sc2, const float* __restrict__ sh2,
    float* __restrict__ out, int t0)
{
    __shared__ __align__(16) ushort As[128 * 40];
    __shared__ __align__(16) ushort Bs[16 * 40];
    int tid = threadIdx.x;
    long r0 = (long)blockIdx.x * 128;
    const ushort* hbase = h_hist + (long)B_ * H_ + r0 * H_;   // slot 1 onward
    int wave = tid >> 6, lane = tid & 63;
    int l15 = lane & 15, quad = lane >> 4;

    f32x4 zero = {0.f, 0.f, 0.f, 0.f};
    f32x4 acc[2]; acc[0] = zero; acc[1] = zero;

    for (int kk = 0; kk < H_ / 32; ++kk) {
        int kb = kk * 32;
        for (int c = tid; c < 512; c += 256) {
            int row = c >> 2, ch = c & 3;
            int k = kb + ch * 8;
            union { uint4 u4; ushort s[8]; } in, ov;
            in.u4 = *(const uint4*)(hbase + (long)row * H_ + k);
            float4 sa = *(const float4*)(sc2 + k), sb = *(const float4*)(sc2 + k + 4);
            float4 ba = *(const float4*)(sh2 + k), bb = *(const float4*)(sh2 + k + 4);
            ov.s[0] = f2bf(fast_tanh(bf2f(in.s[0]) * sa.x + ba.x));
            ov.s[1] = f2bf(fast_tanh(bf2f(in.s[1]) * sa.y + ba.y));
            ov.s[2] = f2bf(fast_tanh(bf2f(in.s[2]) * sa.z + ba.z));
            ov.s[3] = f2bf(fast_tanh(bf2f(in.s[3]) * sa.w + ba.w));
            ov.s[4] = f2bf(fast_tanh(bf2f(in.s[4]) * sb.x + bb.x));
            ov.s[5] = f2bf(fast_tanh(bf2f(in.s[5]) * sb.y + bb.y));
            ov.s[6] = f2bf(fast_tanh(bf2f(in.s[6]) * sb.z + bb.z));
            ov.s[7] = f2bf(fast_tanh(bf2f(in.s[7]) * sb.w + bb.w));
            *(uint4*)&As[row * 40 + ch * 8] = ov.u4;
        }
        if (tid < 64) {
            int row = tid >> 2, ch = tid & 3;
            *(uint4*)&Bs[row * 40 + ch * 8] = *(const uint4*)(woutT + row * H_ + kb + ch * 8);
        }
        __syncthreads();
        s16x8 bfr = *(const s16x8*)&Bs[l15 * 40 + quad * 8];
        for (int i = 0; i < 2; i++) {
            s16x8 af = *(const s16x8*)&As[(wave * 32 + i * 16 + l15) * 40 + quad * 8];
            acc[i] = __builtin_amdgcn_mfma_f32_16x16x32_bf16(af, bfr, acc[i], 0, 0, 0);
        }
        __syncthreads();
    }
    if (l15 < C_) {
        for (int i = 0; i < 2; i++)
            for (int r = 0; r < 4; r++) {
                long rg = r0 + wave * 32 + i * 16 + quad * 4 + r;  // = tl*B + b
                int tl = (int)(rg >> 8);
                int b  = (int)(rg & (B_ - 1));
                out[((long)b * T_ + t0 + tl) * C_ + l15] = acc[i][r];
            }
    }
}

extern "C" void kernel_launch(void* const* d_in, const int* in_sizes, int n_in,
                              void* d_out, int out_size, void* d_ws, size_t ws_size,
                              hipStream_t stream)
{
    const float* x       = (const float*)d_in[0];
    const float* W_fe    = (const float*)d_in[1];
    const float* b_fe    = (const float*)d_in[2];
    const float* gamma1  = (const float*)d_in[3];
    const float* beta1   = (const float*)d_in[4];
    const float* mean1   = (const float*)d_in[5];
    const float* var1    = (const float*)d_in[6];
    const float* kernelw = (const float*)d_in[7];
    const float* reck    = (const float*)d_in[8];
    const float* bias    = (const float*)d_in[9];
    const float* peep_i  = (const float*)d_in[10];
    const float* peep_f  = (const float*)d_in[11];
    const float* peep_o  = (const float*)d_in[12];
    const float* gamma2  = (const float*)d_in[13];
    const float* beta2   = (const float*)d_in[14];
    const float* mean2   = (const float*)d_in[15];
    const float* var2    = (const float*)d_in[16];
    const float* W_out   = (const float*)d_in[17];
    float* out = (float*)d_out;

    char* ws = (char*)d_ws;
    size_t o = 0;
    ushort* wfeT  = (ushort*)(ws + o); o += (size_t)H_ * FP_ * 2;              // 1.64 MB
    ushort* kT2   = (ushort*)(ws + o); o += (size_t)NG_ * H_ * 2;              // 8.39 MB
    ushort* rT2   = (ushort*)(ws + o); o += (size_t)NG_ * H_ * 2;              // 8.39 MB
    ushort* xbf_c = (ushort*)(ws + o); o += (size_t)MC_ * FP_ * 2;             // 6.55 MB
    ushort* feat_c= (ushort*)(ws + o); o += (size_t)MC_ * H_ * 2;              // 8.39 MB
    ushort* zx_c  = (ushort*)(ws + o); o += (size_t)MC_ * NG_ * 2;             // 33.55 MB
    ushort* h_hist= (ushort*)(ws + o); o += (size_t)(TC_ + 1) * B_ * H_ * 2;   // 8.91 MB
    float*  c_buf = (float*)(ws + o);  o += (size_t)B_ * H_ * 4;               // 1.05 MB
    float*  sc1   = (float*)(ws + o);  o += 4096;
    float*  sh1   = (float*)(ws + o);  o += 4096;
    float*  sc2   = (float*)(ws + o);  o += 4096;
    float*  sh2   = (float*)(ws + o);  o += 4096;
    ushort* woutT = (ushort*)(ws + o); o += 16 * H_ * 2;
    unsigned* bar = (unsigned*)(ws + o); o += 2048;
    // total ~77 MB

    prep_params<<<dim3(B_ * H_ / 256), dim3(256), 0, stream>>>(
        gamma1, beta1, mean1, var1, gamma2, beta2, mean2, var2, W_out,
        sc1, sh1, sc2, sh2, woutT, c_buf, h_hist, bar);

    transpose_f32_to_bf16<<<dim3(32, 25), dim3(256), 0, stream>>>(W_fe, wfeT, F_, H_, FP_);
    transpose_perm_bf16<<<dim3(128, 32), dim3(256), 0, stream>>>(kernelw, kT2);
    transpose_perm_bf16<<<dim3(128, 32), dim3(256), 0, stream>>>(reck, rT2);

    for (int ci = 0; ci < T_ / TC_; ++ci) {
        int t0 = ci * TC_;
        convert_x<<<dim3(MC_ * FP_ / 8 / 256), dim3(256), 0, stream>>>(x, xbf_c, t0);
        gemm1_c<<<dim3(H_ / 128, MC_ / 128), dim3(256), 0, stream>>>(
            xbf_c, wfeT, b_fe, sc1, sh1, feat_c);
        gemm2_c<<<dim3(NG_ / 128, MC_ / 128), dim3(256), 0, stream>>>(feat_c, kT2, zx_c);
        lstm_chunk<<<dim3(256), dim3(512), 0, stream>>>(
            h_hist, c_buf, rT2, zx_c, bias, peep_i, peep_f, peep_o, bar, ci);
        final_chunk<<<dim3(MC_ / 128), dim3(256), 0, stream>>>(
            h_hist, woutT, sc2, sh2, out, t0);
    }
}